// Round 3
// baseline (636.149 us; speedup 1.0000x reference)
//
#include <hip/hip_runtime.h>
#include <hip/hip_bf16.h>

// Problem constants
#define NT   1000
#define NS   2048
#define NH   16
#define NR   8
#define HS   256
#define TOUT 993   // NT - NR + 1

typedef __attribute__((ext_vector_type(8))) short short8;
typedef __attribute__((ext_vector_type(4))) float f32x4;

__device__ __forceinline__ ushort f2bf(float f) {
    union { float f; unsigned int u; } v; v.f = f;
    unsigned int u = v.u;
    return (ushort)((u + 0x7fffu + ((u >> 16) & 1u)) >> 16);
}
__device__ __forceinline__ float bf2f(ushort u) {
    union { unsigned int i; float f; } v; v.i = ((unsigned int)u) << 16; return v.f;
}
__device__ __forceinline__ unsigned int packbf2(float lo, float hi) {
    union { __hip_bfloat162 b; unsigned int u; } v;
    v.b = __float22bfloat162_rn(make_float2(lo, hi));
    return v.u;
}
__device__ __forceinline__ float sigf(float x) { return 1.f / (1.f + __expf(-x)); }
__device__ __forceinline__ float fast_tanh(float z) {
    float e = exp2f(z * 2.885390082f);
    return 1.f - 2.f * __builtin_amdgcn_rcpf(e + 1.f);
}
template<int CTRL>
__device__ __forceinline__ float dpp_add(float v) {
    int s = __builtin_amdgcn_update_dpp(0, __builtin_bit_cast(int, v), CTRL, 0xf, 0xf, true);
    return v + __builtin_bit_cast(float, s);
}

// params planes: 0 kp, 1 ks, 2 kd, 3 gd, 4 gl, 5 qb, 6 gi, 7 1-gi, 8 1-kd,
//                9 1-gd, 10 ge, 11..18 wrga
// ---------------- Kernel A: per-site setup ----------------
__global__ __launch_bounds__(256) void kA(
    const float* __restrict__ xc, const float* __restrict__ W_fc, const float* __restrict__ b_fc,
    const float* __restrict__ W_r, const float* __restrict__ b_r,
    const float* __restrict__ W_g, const float* __restrict__ b_g,
    const float* __restrict__ W_kin, const float* __restrict__ b_kin,
    const float* __restrict__ W_kout,
    float* __restrict__ stateK, float* __restrict__ params,
    ushort* __restrict__ Wt_g, ushort* __restrict__ whlo_g)
{
    __shared__ float xcs[32];
    __shared__ float hG[256];
    __shared__ float pGR[288];
    const int s = blockIdx.x, tid = threadIdx.x;

    if (tid < 32) xcs[tid] = xc[s * 32 + tid];
    __syncthreads();

    float acc = b_fc[tid];
#pragma unroll 8
    for (int k = 0; k < 32; ++k) acc = fmaf(xcs[k], W_fc[k * 256 + tid], acc);
    stateK[s * 256 + tid] = acc + b_kin[tid];
    hG[tid] = tanhf(acc);
    __syncthreads();

    for (int j = tid; j < 288; j += 256) {
        const float* W = (j < 144) ? W_g : W_r;
        const float* b = (j < 144) ? b_g : b_r;
        int col = (j < 144) ? j : (j - 144);
        float a = b[col];
#pragma unroll 4
        for (int k = 0; k < 256; ++k) a = fmaf(hG[k], W[k * 144 + col], a);
        pGR[j] = a;
    }
    __syncthreads();

    if (tid < 16) {
        const int h = tid;
        float g0 = pGR[h],       g1 = pGR[16 + h],  g2 = pGR[32 + h];
        float g3 = pGR[48 + h],  g4 = pGR[64 + h],  g5 = pGR[80 + h];
        float g6 = pGR[96 + h],  g7 = pGR[112 + h], g8 = pGR[128 + h];
        float kp = sigf(g0), ksg = sigf(g1), kd = sigf(g2), gd = sigf(g3);
        float t4 = sigf(g4) * 10.f; float gl = t4 * t4 * t4;
        float qb = fmaxf(g5, 0.f) * 0.1f;
        float gi = fminf(fmaxf(g7 * (1.f / 6.f) + 0.5f, 0.f), 1.f) * 0.5f;
        float ge = fmaxf(g8, 0.f);
        float m = g6;
        for (int o = 1; o < 16; o <<= 1) m = fmaxf(m, __shfl_xor(m, o));
        float e = __expf(g6 - m), esum = e;
        for (int o = 1; o < 16; o <<= 1) esum += __shfl_xor(esum, o);
        float ga = e / esum;
        float r[9], rm = -1e30f;
#pragma unroll
        for (int i = 0; i < 9; ++i) { r[i] = pGR[144 + h * 9 + i]; rm = fmaxf(rm, r[i]); }
        float er[9], es = 0.f;
#pragma unroll
        for (int i = 0; i < 9; ++i) { er[i] = __expf(r[i] - rm); es += er[i]; }
        float inv_es = 1.f / es, c = 0.f, wsum = 0.f, w[8];
#pragma unroll
        for (int i = 0; i < 8; ++i) {
            float si = er[i] * inv_es; c += si;
            float wi = fminf(c, 1.f - c + si);
            w[i] = wi; wsum += wi;
        }
        const int base = s * 16 + h;
        params[0 * 32768 + base] = kp;       params[1 * 32768 + base] = ksg;
        params[2 * 32768 + base] = kd;       params[3 * 32768 + base] = gd;
        params[4 * 32768 + base] = gl;       params[5 * 32768 + base] = qb;
        params[6 * 32768 + base] = gi;       params[7 * 32768 + base] = 1.f - gi;
        params[8 * 32768 + base] = 1.f - kd; params[9 * 32768 + base] = 1.f - gd;
        params[10 * 32768 + base] = ge;
        float sc = ga / wsum;
#pragma unroll
        for (int i = 0; i < 8; ++i) params[(11 + i) * 32768 + base] = w[i] * sc;
    }

    if (s == 0) {
        // Wt_g: W_kout^T in bf16, stride 264, rows permuted so k-slot p of the
        // second MFMA (p = q*8+j within each 32-chunk) holds hidden
        // h = (j<4 ? 4q+j : 16+4q+(j-4)) — the order tanh(Z) falls out of the
        // first MFMA's D layout (col=lane&15=site, row=4q+reg=hidden).
        for (int i = tid; i < 48 * 256; i += 256) {
            int col = i % 48, slot = i / 48;
            int kk = slot >> 5, q = (slot >> 3) & 3, j = slot & 7;
            int h = kk * 32 + ((j < 4) ? (q * 4 + j) : (16 + q * 4 + (j - 4)));
            Wt_g[col * 264 + slot] = f2bf(W_kout[h * 48 + col]);
        }
        // whlo_g[h*8 + f]     = bf16 hi part of W_kin[f][h]
        // whlo_g[h*8 + 4 + f] = bf16 lo part (residual)
        {
            const int h = tid;
#pragma unroll
            for (int f = 0; f < 4; ++f) {
                float w = W_kin[f * 256 + h];
                ushort hi = f2bf(w);
                float lo = w - bf2f(hi);
                whlo_g[h * 8 + f] = hi;
                whlo_g[h * 8 + 4 + f] = f2bf(lo);
            }
        }
    }
}

// ---------------- Kernel B v11: r1 inner (MFMA first layer + v_exp tanh), [site][t][h] epilogue ----------------
// r2 post-mortem: poly tanh scalarized and ADDED ~6k VALU cy/wave; v_exp/v_rcp are
// quarter-rate (cheap). Reverted to the measured-best r1 inner loop.
// Epilogue layout changed to kmki/kevA[site][t][h] so kC can run 16-lane waves coalesced.
__global__ __launch_bounds__(256, 3) void kB(
    const float* __restrict__ x,
    const float* __restrict__ stateK, const float* __restrict__ b_kout,
    const ushort* __restrict__ Wt_g, const ushort* __restrict__ whlo_g,
    const float* __restrict__ params,
    unsigned int* __restrict__ kmki, ushort* __restrict__ kevA,
    float2* __restrict__ pspl)
{
    __shared__ ushort Wt[48 * 264];    // 25,344 B
    __shared__ float  stS[16 * 260];   // 16,640 B
    __shared__ ushort whloS[2048];     //  4,096 B  [hidden][8: wh0..3, wl0..3]
    __shared__ float  geS[256];        //  1,024 B  [site_local*16 + h]
    __shared__ float  evS[4][5][16];   //  1,280 B  [wave][ti][site_local]
    const int tid = threadIdx.x;
    const int st = blockIdx.x & 127;   // site tile (0..127)
    const int tg = blockIdx.x >> 7;    // t group (0..49)
    const int s0 = st << 4;

    for (int i = tid; i < 3168; i += 256)
        ((uint2*)Wt)[i] = ((const uint2*)Wt_g)[i];
#pragma unroll
    for (int i = tid; i < 1024; i += 256) {
        int row = i >> 6, c = (i & 63) << 2;
        *(float4*)(stS + row * 260 + c) = *(const float4*)(stateK + (s0 + row) * 256 + c);
    }
    *(float4*)(whloS + tid * 8) = ((const float4*)whlo_g)[tid];
    geS[tid] = params[10 * 32768 + s0 * 16 + tid];
    __syncthreads();

    const int wv = tid >> 6, lane = tid & 63;
    const int mi = lane & 15, quad = lane >> 4;
    const int site = s0 + mi;
    const int t0 = tg * 20 + wv * 5;   // 50*20 = 1000, guard-free

    float xf[5][4];
#pragma unroll
    for (int ti = 0; ti < 5; ++ti) {
        const int t = t0 + ti;
        const int xb = (t * 2048 + site) * 6;
        float2 u23 = *(const float2*)(x + xb + 2);
        float2 u45 = *(const float2*)(x + xb + 4);
        xf[ti][0] = u23.x; xf[ti][1] = u23.y; xf[ti][2] = u45.x; xf[ti][3] = u45.y;
        if (lane < 16) {   // quad 0: ps/pl in [sg][t][sl] layout, ev tile in LDS
            float2 u01 = *(const float2*)(x + xb);
            float fl = fminf(fmaxf(u23.y * __builtin_amdgcn_rcpf(u23.y - u23.x + 1e-5f), 0.f), 1.f);
            const int sg = st * 4 + (mi >> 2), sl = mi & 3;
            pspl[(sg * 1000 + t) * 4 + sl] = make_float2(u01.x * (1.f - fl), u01.x * fl);
            evS[wv][ti][mi] = u01.y;
        }
    }

    // Feature B-fragments (built once per ti, reused across all 8 kk):
    // q=0: {fh01, fh23, fh01, fh23}; q=1: {fl01, fl23, 0, 0}; q>=2: 0.
    unsigned int bfr[5][4];
#pragma unroll
    for (int ti = 0; ti < 5; ++ti) {
        const float x0 = xf[ti][0], x1 = xf[ti][1], x2 = xf[ti][2], x3 = xf[ti][3];
        unsigned int h01 = packbf2(x0, x1), h23 = packbf2(x2, x3);
        float l0 = x0 - bf2f((ushort)(h01 & 0xffffu));
        float l1 = x1 - bf2f((ushort)(h01 >> 16));
        float l2 = x2 - bf2f((ushort)(h23 & 0xffffu));
        float l3 = x3 - bf2f((ushort)(h23 >> 16));
        unsigned int l01 = packbf2(l0, l1), l23 = packbf2(l2, l3);
        bfr[ti][0] = (quad == 0) ? h01 : (quad == 1 ? l01 : 0u);
        bfr[ti][1] = (quad == 0) ? h23 : (quad == 1 ? l23 : 0u);
        bfr[ti][2] = (quad == 0) ? h01 : 0u;
        bfr[ti][3] = (quad == 0) ? h23 : 0u;
    }

    const float*  stp = stS + mi * 260;
    const ushort* Wt0 = Wt + mi * 264 + quad * 8;
    const int q4 = quad * 4;

    f32x4 acc[5][3];
#pragma unroll
    for (int ti = 0; ti < 5; ++ti)
#pragma unroll
        for (int j = 0; j < 3; ++j) acc[ti][j] = (f32x4){0.f, 0.f, 0.f, 0.f};

#pragma unroll 1
    for (int kk = 0; kk < 8; ++kk) {
        const int ko = kk * 32;
        // A fragments (W_kin^T): row = lane&15 = hidden-within-16 of each tile.
        // q=0: {wh0..3, wl0..3} (whlo row direct); q=1: {wh0..3, 0}; q>=2: 0.
        union { short8 s; unsigned int u[4]; } W0, W1, A0, A1;
        W0.s = *(const short8*)(whloS + (ko + mi) * 8);
        W1.s = *(const short8*)(whloS + (ko + 16 + mi) * 8);
        A0.u[0] = (quad <= 1) ? W0.u[0] : 0u;
        A0.u[1] = (quad <= 1) ? W0.u[1] : 0u;
        A0.u[2] = (quad == 0) ? W0.u[2] : 0u;
        A0.u[3] = (quad == 0) ? W0.u[3] : 0u;
        A1.u[0] = (quad <= 1) ? W1.u[0] : 0u;
        A1.u[1] = (quad <= 1) ? W1.u[1] : 0u;
        A1.u[2] = (quad == 0) ? W1.u[2] : 0u;
        A1.u[3] = (quad == 0) ? W1.u[3] : 0u;
        // C-in = state tile: C[reg] = state[site=mi][ko + tile*16 + 4q + reg]
        f32x4 c0 = *(const f32x4*)(stp + ko + q4);
        f32x4 c1 = *(const f32x4*)(stp + ko + 16 + q4);
        short8 b0 = *(const short8*)(Wt0 + ko);
        short8 b1 = *(const short8*)(Wt0 + 16 * 264 + ko);
        short8 b2 = *(const short8*)(Wt0 + 32 * 264 + ko);
#pragma unroll
        for (int ti = 0; ti < 5; ++ti) {
            union { short8 s; unsigned int u[4]; } B;
            B.u[0] = bfr[ti][0]; B.u[1] = bfr[ti][1];
            B.u[2] = bfr[ti][2]; B.u[3] = bfr[ti][3];
            f32x4 z0 = __builtin_amdgcn_mfma_f32_16x16x32_bf16(A0.s, B.s, c0, 0, 0, 0);
            f32x4 z1 = __builtin_amdgcn_mfma_f32_16x16x32_bf16(A1.s, B.s, c1, 0, 0, 0);
            union { short8 s; unsigned int u[4]; } a;
            a.u[0] = packbf2(fast_tanh(z0[0]), fast_tanh(z0[1]));
            a.u[1] = packbf2(fast_tanh(z0[2]), fast_tanh(z0[3]));
            a.u[2] = packbf2(fast_tanh(z1[0]), fast_tanh(z1[1]));
            a.u[3] = packbf2(fast_tanh(z1[2]), fast_tanh(z1[3]));
            acc[ti][0] = __builtin_amdgcn_mfma_f32_16x16x32_bf16(a.s, b0, acc[ti][0], 0, 0, 0);
            acc[ti][1] = __builtin_amdgcn_mfma_f32_16x16x32_bf16(a.s, b1, acc[ti][1], 0, 0, 0);
            acc[ti][2] = __builtin_amdgcn_mfma_f32_16x16x32_bf16(a.s, b2, acc[ti][2], 0, 0, 0);
        }
    }

    // epilogue: D row = quad*4+reg (site_local), col = mi (head)
    // NEW layout: kmki/kevA[site][t][h] — per store instr 4x64B (kmki) / 4x32B (kevA)
    // segments, 64B-granule coalesced; enables 16-lane coalesced reads in kC.
    const float bo0 = b_kout[mi], bo1 = b_kout[16 + mi], bo2 = b_kout[32 + mi];
#pragma unroll
    for (int ti = 0; ti < 5; ++ti) {
        const int t = t0 + ti;
#pragma unroll
        for (int reg = 0; reg < 4; ++reg) {
            const int sl = quad * 4 + reg;
            float km = __expf(acc[ti][0][reg] + bo0);
            float ki = fmaxf(acc[ti][1][reg] + bo1, 0.f);
            float ke = __expf(acc[ti][2][reg] + bo2);
            float kev = ke * evS[wv][ti][sl] * geS[sl * 16 + mi];
            const int idx = ((s0 + sl) * 1000 + t) * 16 + mi;
            kmki[idx] = (unsigned int)f2bf(km) | ((unsigned int)f2bf(ki) << 16);
            kevA[idx] = f2bf(kev);
        }
    }
}

// ---------------- Kernel C v10: one site per wave (16 active lanes), 4x wave count ----------------
// r1 budget by elimination: kC ~= 230 us at 0.93 TB/s (213 MB reads; 34 us BW floor).
// With 512 single-wave blocks (0.5 waves/SIMD), per-CU outstanding-load occupancy and
// load-issue duty cycle bind. 2048 blocks x 1 site/wave -> 8 waves/CU: 4x contexts.
// Triple-buffer distance-2 kept; dpp 16-lane butterfly is row-local so lanes 16+ exit.
__global__ __launch_bounds__(64, 1) void kC(
    const unsigned int* __restrict__ kmki, const ushort* __restrict__ kevA,
    const float2* __restrict__ pspl,
    const float* __restrict__ params, float* __restrict__ yOut)
{
    const int tid = threadIdx.x;
    if (tid >= 16) return;
    const int s = blockIdx.x;               // one site per block/wave
    const int h = tid;
    const int gid = s * 16 + h;

    const float kp  = params[0 * 32768 + gid];
    const float ks_ = params[1 * 32768 + gid];
    const float kd  = params[2 * 32768 + gid];
    const float gd  = params[3 * 32768 + gid];
    const float gl  = params[4 * 32768 + gid];
    const float qbv = params[5 * 32768 + gid];
    const float gi  = params[6 * 32768 + gid];
    const float gi1 = params[7 * 32768 + gid];
    const float kd1 = params[8 * 32768 + gid];
    const float gd1 = params[9 * 32768 + gid];
    float wrga[8];
#pragma unroll
    for (int i = 0; i < 8; ++i) wrga[i] = params[(11 + i) * 32768 + gid];

    float Sf = 0.f, Ss = 0.f, Sg = 0.f;
    float qh[8];
#pragma unroll
    for (int i = 0; i < 8; ++i) qh[i] = 0.f;

    const int base = s * 1000;              // [site][t][h] layout
    const int psb  = (s >> 2) * 4000 + (s & 3);   // pspl stays [sg][t][sl]

    unsigned int a0[8], a1[8], a2[8]; ushort e0[8], e1[8], e2[8];
    float2 p0[8], p1[8], p2[8];

#define LOADB(B, tb) do {                                               \
        const int _b = base + (tb) * 8;                                 \
        const int _p = psb + (tb) * 32;                                 \
        _Pragma("unroll")                                               \
        for (int i = 0; i < 8; ++i) {                                   \
            a##B[i] = kmki[(_b + i) * 16 + h];                          \
            e##B[i] = kevA[(_b + i) * 16 + h];                          \
            p##B[i] = pspl[_p + i * 4];                                 \
        }                                                               \
    } while (0)

#define COMPUTEB(B, tb) do {                                            \
        float z[8];                                                     \
        _Pragma("unroll")                                               \
        for (int i = 0; i < 8; ++i) {                                   \
            float km = __builtin_bit_cast(float, a##B[i] << 16);        \
            float ki = __builtin_bit_cast(float, a##B[i] & 0xffff0000u);\
            float kev = __builtin_bit_cast(float, ((unsigned int)e##B[i]) << 16); \
            float ps = p##B[i].x, pl = p##B[i].y;                       \
            Sf += ps;                                                   \
            float qf = fminf(Sf, km); Sf -= qf;                         \
            float inflow = qf + pl;                                     \
            float qd = inflow * gi;                                     \
            Ss = fmaf(inflow, gi1, Ss);                                 \
            float E = fminf(Ss, kev); Ss -= E;                          \
            float qi = fminf(ki, Ss); Ss -= qi;                         \
            float qp = kp * fmaxf(Ss - gl, 0.f);                        \
            float qsa = ks_ * fminf(Ss, gl);                            \
            Ss -= qp + qsa;                                             \
            Sg = fmaf(qsa, gd, Sg);                                     \
            float qg = fmaf(kd, Sg, qbv);                               \
            Sg *= kd1;                                                  \
            float q = fmaf(qsa, gd1, qp) + qg + qd + qi;                \
            qh[i] = q;                                                  \
            float v = 0.f;                                              \
            _Pragma("unroll")                                           \
            for (int k = 0; k < 8; ++k) v = fmaf(wrga[k], qh[(i - k) & 7], v); \
            z[i] = v;                                                   \
        }                                                               \
        _Pragma("unroll")                                               \
        for (int i = 0; i < 8; ++i) z[i] = dpp_add<0xB1>(z[i]);         \
        _Pragma("unroll")                                               \
        for (int i = 0; i < 8; ++i) z[i] = dpp_add<0x4E>(z[i]);         \
        _Pragma("unroll")                                               \
        for (int i = 0; i < 8; ++i) z[i] = dpp_add<0x141>(z[i]);        \
        _Pragma("unroll")                                               \
        for (int i = 0; i < 8; ++i) z[i] = dpp_add<0x140>(z[i]);        \
        if (h == 0) {                                                   \
            const int tbase = (tb) * 8;                                 \
            _Pragma("unroll")                                           \
            for (int i = 0; i < 8; ++i) {                               \
                const int t = tbase + i;                                \
                if (t >= 7) yOut[(t - 7) * 2048 + s] = z[i];            \
            }                                                           \
        }                                                               \
    } while (0)

    LOADB(0, 0);
    LOADB(1, 1);
    LOADB(2, 2);

    // 125 batches; 42 chunks of 3 (126 slots, last compute guarded).
    for (int it = 0; it < 42; ++it) {
        const int tb = it * 3;
        COMPUTEB(0, tb);
        LOADB(0, (tb + 3 <= 124) ? tb + 3 : 124);
        if (tb + 1 < 125) {
            COMPUTEB(1, tb + 1);
            LOADB(1, (tb + 4 <= 124) ? tb + 4 : 124);
        }
        if (tb + 2 < 125) {
            COMPUTEB(2, tb + 2);
            LOADB(2, (tb + 5 <= 124) ? tb + 5 : 124);
        }
    }
#undef LOADB
#undef COMPUTEB
}

// ---------------- launch ----------------
extern "C" void kernel_launch(void* const* d_in, const int* in_sizes, int n_in,
                              void* d_out, int out_size, void* d_ws, size_t ws_size,
                              hipStream_t stream) {
    const float* x      = (const float*)d_in[0];
    const float* xc     = (const float*)d_in[1];
    const float* W_fc   = (const float*)d_in[2];
    const float* b_fc   = (const float*)d_in[3];
    const float* W_r    = (const float*)d_in[4];
    const float* b_r    = (const float*)d_in[5];
    const float* W_g    = (const float*)d_in[6];
    const float* b_g    = (const float*)d_in[7];
    const float* W_kin  = (const float*)d_in[8];
    const float* b_kin  = (const float*)d_in[9];
    const float* W_kout = (const float*)d_in[10];
    const float* b_kout = (const float*)d_in[11];
    float* yOut = (float*)d_out;

    char* ws = (char*)d_ws;
    float*  stateK = (float*)(ws + 0);                        // 2 MB
    float*  params = (float*)(ws + (2 << 20));                // 19 planes (reserve 4 MB)
    ushort* Wt_g   = (ushort*)(ws + (6 << 20));               // 25,344 B
    ushort* whlo_g = (ushort*)(ws + (6 << 20) + (64 << 10));  // 4,096 B (within 128 KiB reserve)
    char*   p      = ws + (6 << 20) + (128 << 10);
    float2* pspl   = (float2*)p;                              // 16,384,000 B
    unsigned int* kmki = (unsigned int*)(p + 16384000);       // 131,072,000 B
    ushort* kevA   = (ushort*)(p + 16384000 + 131072000);     //  65,536,000 B

    hipLaunchKernelGGL(kA, dim3(2048), dim3(256), 0, stream,
                       xc, W_fc, b_fc, W_r, b_r, W_g, b_g, W_kin, b_kin, W_kout,
                       stateK, params, Wt_g, whlo_g);
    hipLaunchKernelGGL(kB, dim3(128 * 50), dim3(256), 0, stream,
                       x, stateK, b_kout, Wt_g, whlo_g, params, kmki, kevA, pspl);
    hipLaunchKernelGGL(kC, dim3(2048), dim3(64), 0, stream,
                       kmki, kevA, pspl, params, yOut);
}

// Round 4
// 528.315 us; speedup vs baseline: 1.2041x; 1.2041x over previous
//
#include <hip/hip_runtime.h>
#include <hip/hip_bf16.h>

// Problem constants
#define NT   1000
#define NS   2048
#define NH   16
#define NR   8
#define HS   256
#define TOUT 993   // NT - NR + 1

typedef __attribute__((ext_vector_type(8))) short short8;
typedef __attribute__((ext_vector_type(4))) float f32x4;

__device__ __forceinline__ ushort f2bf(float f) {
    union { float f; unsigned int u; } v; v.f = f;
    unsigned int u = v.u;
    return (ushort)((u + 0x7fffu + ((u >> 16) & 1u)) >> 16);
}
__device__ __forceinline__ float bf2f(ushort u) {
    union { unsigned int i; float f; } v; v.i = ((unsigned int)u) << 16; return v.f;
}
__device__ __forceinline__ unsigned int packbf2(float lo, float hi) {
    union { __hip_bfloat162 b; unsigned int u; } v;
    v.b = __float22bfloat162_rn(make_float2(lo, hi));
    return v.u;
}
__device__ __forceinline__ float sigf(float x) { return 1.f / (1.f + __expf(-x)); }
__device__ __forceinline__ float fast_tanh(float z) {
    float e = exp2f(z * 2.885390082f);
    return 1.f - 2.f * __builtin_amdgcn_rcpf(e + 1.f);
}
template<int CTRL>
__device__ __forceinline__ float dpp_add(float v) {
    int s = __builtin_amdgcn_update_dpp(0, __builtin_bit_cast(int, v), CTRL, 0xf, 0xf, true);
    return v + __builtin_bit_cast(float, s);
}
// async global->LDS DMA: zero result VGPRs, counted by vmcnt.
// LDS dest = wave-uniform base + lane*size; global src is per-lane.
__device__ __forceinline__ void gll16(const void* g, void* l) {
    __builtin_amdgcn_global_load_lds((const __attribute__((address_space(1))) unsigned int*)g,
                                     (__attribute__((address_space(3))) unsigned int*)l, 16, 0, 0);
}
__device__ __forceinline__ void gll4(const void* g, void* l) {
    __builtin_amdgcn_global_load_lds((const __attribute__((address_space(1))) unsigned int*)g,
                                     (__attribute__((address_space(3))) unsigned int*)l, 4, 0, 0);
}

// params planes: 0 kp, 1 ks, 2 kd, 3 gd, 4 gl, 5 qb, 6 gi, 7 1-gi, 8 1-kd,
//                9 1-gd, 10 ge, 11..18 wrga
// ---------------- Kernel A: per-site setup ----------------
__global__ __launch_bounds__(256) void kA(
    const float* __restrict__ xc, const float* __restrict__ W_fc, const float* __restrict__ b_fc,
    const float* __restrict__ W_r, const float* __restrict__ b_r,
    const float* __restrict__ W_g, const float* __restrict__ b_g,
    const float* __restrict__ W_kin, const float* __restrict__ b_kin,
    const float* __restrict__ W_kout,
    float* __restrict__ stateK, float* __restrict__ params,
    ushort* __restrict__ Wt_g, ushort* __restrict__ whlo_g)
{
    __shared__ float xcs[32];
    __shared__ float hG[256];
    __shared__ float pGR[288];
    const int s = blockIdx.x, tid = threadIdx.x;

    if (tid < 32) xcs[tid] = xc[s * 32 + tid];
    __syncthreads();

    float acc = b_fc[tid];
#pragma unroll 8
    for (int k = 0; k < 32; ++k) acc = fmaf(xcs[k], W_fc[k * 256 + tid], acc);
    stateK[s * 256 + tid] = acc + b_kin[tid];
    hG[tid] = tanhf(acc);
    __syncthreads();

    for (int j = tid; j < 288; j += 256) {
        const float* W = (j < 144) ? W_g : W_r;
        const float* b = (j < 144) ? b_g : b_r;
        int col = (j < 144) ? j : (j - 144);
        float a = b[col];
#pragma unroll 4
        for (int k = 0; k < 256; ++k) a = fmaf(hG[k], W[k * 144 + col], a);
        pGR[j] = a;
    }
    __syncthreads();

    if (tid < 16) {
        const int h = tid;
        float g0 = pGR[h],       g1 = pGR[16 + h],  g2 = pGR[32 + h];
        float g3 = pGR[48 + h],  g4 = pGR[64 + h],  g5 = pGR[80 + h];
        float g6 = pGR[96 + h],  g7 = pGR[112 + h], g8 = pGR[128 + h];
        float kp = sigf(g0), ksg = sigf(g1), kd = sigf(g2), gd = sigf(g3);
        float t4 = sigf(g4) * 10.f; float gl = t4 * t4 * t4;
        float qb = fmaxf(g5, 0.f) * 0.1f;
        float gi = fminf(fmaxf(g7 * (1.f / 6.f) + 0.5f, 0.f), 1.f) * 0.5f;
        float ge = fmaxf(g8, 0.f);
        float m = g6;
        for (int o = 1; o < 16; o <<= 1) m = fmaxf(m, __shfl_xor(m, o));
        float e = __expf(g6 - m), esum = e;
        for (int o = 1; o < 16; o <<= 1) esum += __shfl_xor(esum, o);
        float ga = e / esum;
        float r[9], rm = -1e30f;
#pragma unroll
        for (int i = 0; i < 9; ++i) { r[i] = pGR[144 + h * 9 + i]; rm = fmaxf(rm, r[i]); }
        float er[9], es = 0.f;
#pragma unroll
        for (int i = 0; i < 9; ++i) { er[i] = __expf(r[i] - rm); es += er[i]; }
        float inv_es = 1.f / es, c = 0.f, wsum = 0.f, w[8];
#pragma unroll
        for (int i = 0; i < 8; ++i) {
            float si = er[i] * inv_es; c += si;
            float wi = fminf(c, 1.f - c + si);
            w[i] = wi; wsum += wi;
        }
        const int base = s * 16 + h;
        params[0 * 32768 + base] = kp;       params[1 * 32768 + base] = ksg;
        params[2 * 32768 + base] = kd;       params[3 * 32768 + base] = gd;
        params[4 * 32768 + base] = gl;       params[5 * 32768 + base] = qb;
        params[6 * 32768 + base] = gi;       params[7 * 32768 + base] = 1.f - gi;
        params[8 * 32768 + base] = 1.f - kd; params[9 * 32768 + base] = 1.f - gd;
        params[10 * 32768 + base] = ge;
        float sc = ga / wsum;
#pragma unroll
        for (int i = 0; i < 8; ++i) params[(11 + i) * 32768 + base] = w[i] * sc;
    }

    if (s == 0) {
        // Wt_g: W_kout^T in bf16, stride 264, rows permuted to match the
        // first-MFMA D layout (see kB).
        for (int i = tid; i < 48 * 256; i += 256) {
            int col = i % 48, slot = i / 48;
            int kk = slot >> 5, q = (slot >> 3) & 3, j = slot & 7;
            int h = kk * 32 + ((j < 4) ? (q * 4 + j) : (16 + q * 4 + (j - 4)));
            Wt_g[col * 264 + slot] = f2bf(W_kout[h * 48 + col]);
        }
        // whlo_g[h*8 + f] = bf16 hi of W_kin[f][h]; +4: lo residual
        {
            const int h = tid;
#pragma unroll
            for (int f = 0; f < 4; ++f) {
                float w = W_kin[f * 256 + h];
                ushort hi = f2bf(w);
                float lo = w - bf2f(hi);
                whlo_g[h * 8 + f] = hi;
                whlo_g[h * 8 + 4 + f] = f2bf(lo);
            }
        }
    }
}

// ---------------- Kernel B v11 (unchanged from r3, measured 261us) ----------------
__global__ __launch_bounds__(256, 3) void kB(
    const float* __restrict__ x,
    const float* __restrict__ stateK, const float* __restrict__ b_kout,
    const ushort* __restrict__ Wt_g, const ushort* __restrict__ whlo_g,
    const float* __restrict__ params,
    unsigned int* __restrict__ kmki, ushort* __restrict__ kevA,
    float2* __restrict__ pspl)
{
    __shared__ ushort Wt[48 * 264];    // 25,344 B
    __shared__ float  stS[16 * 260];   // 16,640 B
    __shared__ ushort whloS[2048];     //  4,096 B  [hidden][8: wh0..3, wl0..3]
    __shared__ float  geS[256];        //  1,024 B  [site_local*16 + h]
    __shared__ float  evS[4][5][16];   //  1,280 B  [wave][ti][site_local]
    const int tid = threadIdx.x;
    const int st = blockIdx.x & 127;   // site tile (0..127)
    const int tg = blockIdx.x >> 7;    // t group (0..49)
    const int s0 = st << 4;

    for (int i = tid; i < 3168; i += 256)
        ((uint2*)Wt)[i] = ((const uint2*)Wt_g)[i];
#pragma unroll
    for (int i = tid; i < 1024; i += 256) {
        int row = i >> 6, c = (i & 63) << 2;
        *(float4*)(stS + row * 260 + c) = *(const float4*)(stateK + (s0 + row) * 256 + c);
    }
    *(float4*)(whloS + tid * 8) = ((const float4*)whlo_g)[tid];
    geS[tid] = params[10 * 32768 + s0 * 16 + tid];
    __syncthreads();

    const int wv = tid >> 6, lane = tid & 63;
    const int mi = lane & 15, quad = lane >> 4;
    const int site = s0 + mi;
    const int t0 = tg * 20 + wv * 5;   // 50*20 = 1000, guard-free

    float xf[5][4];
#pragma unroll
    for (int ti = 0; ti < 5; ++ti) {
        const int t = t0 + ti;
        const int xb = (t * 2048 + site) * 6;
        float2 u23 = *(const float2*)(x + xb + 2);
        float2 u45 = *(const float2*)(x + xb + 4);
        xf[ti][0] = u23.x; xf[ti][1] = u23.y; xf[ti][2] = u45.x; xf[ti][3] = u45.y;
        if (lane < 16) {   // quad 0: ps/pl in [sg][t][sl] layout, ev tile in LDS
            float2 u01 = *(const float2*)(x + xb);
            float fl = fminf(fmaxf(u23.y * __builtin_amdgcn_rcpf(u23.y - u23.x + 1e-5f), 0.f), 1.f);
            const int sg = st * 4 + (mi >> 2), sl = mi & 3;
            pspl[(sg * 1000 + t) * 4 + sl] = make_float2(u01.x * (1.f - fl), u01.x * fl);
            evS[wv][ti][mi] = u01.y;
        }
    }

    // Feature B-fragments (built once per ti, reused across all 8 kk):
    // q=0: {fh01, fh23, fh01, fh23}; q=1: {fl01, fl23, 0, 0}; q>=2: 0.
    unsigned int bfr[5][4];
#pragma unroll
    for (int ti = 0; ti < 5; ++ti) {
        const float x0 = xf[ti][0], x1 = xf[ti][1], x2 = xf[ti][2], x3 = xf[ti][3];
        unsigned int h01 = packbf2(x0, x1), h23 = packbf2(x2, x3);
        float l0 = x0 - bf2f((ushort)(h01 & 0xffffu));
        float l1 = x1 - bf2f((ushort)(h01 >> 16));
        float l2 = x2 - bf2f((ushort)(h23 & 0xffffu));
        float l3 = x3 - bf2f((ushort)(h23 >> 16));
        unsigned int l01 = packbf2(l0, l1), l23 = packbf2(l2, l3);
        bfr[ti][0] = (quad == 0) ? h01 : (quad == 1 ? l01 : 0u);
        bfr[ti][1] = (quad == 0) ? h23 : (quad == 1 ? l23 : 0u);
        bfr[ti][2] = (quad == 0) ? h01 : 0u;
        bfr[ti][3] = (quad == 0) ? h23 : 0u;
    }

    const float*  stp = stS + mi * 260;
    const ushort* Wt0 = Wt + mi * 264 + quad * 8;
    const int q4 = quad * 4;

    f32x4 acc[5][3];
#pragma unroll
    for (int ti = 0; ti < 5; ++ti)
#pragma unroll
        for (int j = 0; j < 3; ++j) acc[ti][j] = (f32x4){0.f, 0.f, 0.f, 0.f};

#pragma unroll 1
    for (int kk = 0; kk < 8; ++kk) {
        const int ko = kk * 32;
        union { short8 s; unsigned int u[4]; } W0, W1, A0, A1;
        W0.s = *(const short8*)(whloS + (ko + mi) * 8);
        W1.s = *(const short8*)(whloS + (ko + 16 + mi) * 8);
        A0.u[0] = (quad <= 1) ? W0.u[0] : 0u;
        A0.u[1] = (quad <= 1) ? W0.u[1] : 0u;
        A0.u[2] = (quad == 0) ? W0.u[2] : 0u;
        A0.u[3] = (quad == 0) ? W0.u[3] : 0u;
        A1.u[0] = (quad <= 1) ? W1.u[0] : 0u;
        A1.u[1] = (quad <= 1) ? W1.u[1] : 0u;
        A1.u[2] = (quad == 0) ? W1.u[2] : 0u;
        A1.u[3] = (quad == 0) ? W1.u[3] : 0u;
        f32x4 c0 = *(const f32x4*)(stp + ko + q4);
        f32x4 c1 = *(const f32x4*)(stp + ko + 16 + q4);
        short8 b0 = *(const short8*)(Wt0 + ko);
        short8 b1 = *(const short8*)(Wt0 + 16 * 264 + ko);
        short8 b2 = *(const short8*)(Wt0 + 32 * 264 + ko);
#pragma unroll
        for (int ti = 0; ti < 5; ++ti) {
            union { short8 s; unsigned int u[4]; } B;
            B.u[0] = bfr[ti][0]; B.u[1] = bfr[ti][1];
            B.u[2] = bfr[ti][2]; B.u[3] = bfr[ti][3];
            f32x4 z0 = __builtin_amdgcn_mfma_f32_16x16x32_bf16(A0.s, B.s, c0, 0, 0, 0);
            f32x4 z1 = __builtin_amdgcn_mfma_f32_16x16x32_bf16(A1.s, B.s, c1, 0, 0, 0);
            union { short8 s; unsigned int u[4]; } a;
            a.u[0] = packbf2(fast_tanh(z0[0]), fast_tanh(z0[1]));
            a.u[1] = packbf2(fast_tanh(z0[2]), fast_tanh(z0[3]));
            a.u[2] = packbf2(fast_tanh(z1[0]), fast_tanh(z1[1]));
            a.u[3] = packbf2(fast_tanh(z1[2]), fast_tanh(z1[3]));
            acc[ti][0] = __builtin_amdgcn_mfma_f32_16x16x32_bf16(a.s, b0, acc[ti][0], 0, 0, 0);
            acc[ti][1] = __builtin_amdgcn_mfma_f32_16x16x32_bf16(a.s, b1, acc[ti][1], 0, 0, 0);
            acc[ti][2] = __builtin_amdgcn_mfma_f32_16x16x32_bf16(a.s, b2, acc[ti][2], 0, 0, 0);
        }
    }

    // epilogue: kmki/kevA[site][t][h]
    const float bo0 = b_kout[mi], bo1 = b_kout[16 + mi], bo2 = b_kout[32 + mi];
#pragma unroll
    for (int ti = 0; ti < 5; ++ti) {
        const int t = t0 + ti;
#pragma unroll
        for (int reg = 0; reg < 4; ++reg) {
            const int sl = quad * 4 + reg;
            float km = __expf(acc[ti][0][reg] + bo0);
            float ki = fmaxf(acc[ti][1][reg] + bo1, 0.f);
            float ke = __expf(acc[ti][2][reg] + bo2);
            float kev = ke * evS[wv][ti][sl] * geS[sl * 16 + mi];
            const int idx = ((s0 + sl) * 1000 + t) * 16 + mi;
            kmki[idx] = (unsigned int)f2bf(km) | ((unsigned int)f2bf(ki) << 16);
            kevA[idx] = f2bf(kev);
        }
    }
}

// ---------------- Kernel C v11: global_load_lds double-buffered chunk pipeline ----------------
// r3 post-mortem: register triple-buffer needs ~140 VGPR, compiler allocated 72 ->
// loads sunk to uses, prefetch silently dead, each batch eats HBM latency.
// Fix: DMA chunks of 64 t into LDS (26x global_load_lds, 0 result VGPRs),
// double-buffer 2x27008B, counted s_waitcnt vmcnt(26) (T4: never drain the prefetch).
// Chunk compute ~4300cy >> 900cy HBM latency -> full overlap. 512 blocks x 1 wave,
// 4 sites/wave, no barriers (single wave). Site regions padded to dodge bank conflicts.
#define KM_STRIDE 4160   // 4096 + 64 pad  (bank offset 16 per site)
#define KE_BASE   16640  // 4*4160
#define KE_STRIDE 2080   // 2048 + 32 pad  (bank offset 8 per site)
#define PS_BASE   24960  // 16640 + 4*2080
#define BUF_SZ    27008  // 24960 + 2048
__global__ __launch_bounds__(64, 1) void kC(
    const unsigned int* __restrict__ kmki, const ushort* __restrict__ kevA,
    const float2* __restrict__ pspl,
    const float* __restrict__ params, float* __restrict__ yOut)
{
    __shared__ char lds[2 * BUF_SZ];   // 54,016 B -> 2 blocks/CU (160KB pool)
    const int tid = threadIdx.x;
    const int sg = blockIdx.x;              // s_group (4 sites per wave)
    const int sl = tid >> 4;
    const int s = sg * 4 + sl;
    const int h = tid & 15;
    const int gid = s * 16 + h;

    const float kp  = params[0 * 32768 + gid];
    const float ks_ = params[1 * 32768 + gid];
    const float kd  = params[2 * 32768 + gid];
    const float gd  = params[3 * 32768 + gid];
    const float gl  = params[4 * 32768 + gid];
    const float qbv = params[5 * 32768 + gid];
    const float gi  = params[6 * 32768 + gid];
    const float gi1 = params[7 * 32768 + gid];
    const float kd1 = params[8 * 32768 + gid];
    const float gd1 = params[9 * 32768 + gid];
    float wrga[8];
#pragma unroll
    for (int i = 0; i < 8; ++i) wrga[i] = params[(11 + i) * 32768 + gid];

    float Sf = 0.f, Ss = 0.f, Sg = 0.f;
    float qh[8];
#pragma unroll
    for (int i = 0; i < 8; ++i) qh[i] = 0.f;

    const char* kmG = (const char*)kmki;   // [site][t][h] uint   -> 64 B/t/site
    const char* keG = (const char*)kevA;   // [site][t][h] ushort -> 32 B/t/site
    const char* psG = (const char*)pspl;   // [sg][t][sl] float2  -> 32 B/t

    // Stage chunk c (64 t; TAIL: 40 t) into buffer c&1. 26 DMA instrs either way.
#define STAGE(c, TAIL) do {                                                     \
        char* L = lds + ((c) & 1) * BUF_SZ;                                     \
        _Pragma("unroll")                                                       \
        for (int q = 0; q < 4; ++q) {                                           \
            const char* gk = kmG + ((size_t)(sg * 4 + q) * 1000 + (c) * 64) * 64; \
            const char* ge = keG + ((size_t)(sg * 4 + q) * 1000 + (c) * 64) * 32; \
            char* lk = L + q * KM_STRIDE;                                       \
            char* le = L + KE_BASE + q * KE_STRIDE;                             \
            if (!(TAIL)) {                                                      \
                _Pragma("unroll")                                               \
                for (int k = 0; k < 4; ++k) gll16(gk + k * 1024 + tid * 16, lk + k * 1024); \
                _Pragma("unroll")                                               \
                for (int k = 0; k < 2; ++k) gll16(ge + k * 1024 + tid * 16, le + k * 1024); \
            } else {                                                            \
                _Pragma("unroll")                                               \
                for (int k = 0; k < 2; ++k) gll16(gk + k * 1024 + tid * 16, lk + k * 1024); \
                _Pragma("unroll")                                               \
                for (int k = 0; k < 2; ++k) gll4(gk + 2048 + k * 256 + tid * 4, lk + 2048 + k * 256); \
                gll16(ge + tid * 16, le);                                       \
                gll4(ge + 1024 + tid * 4, le + 1024);                           \
            }                                                                   \
        }                                                                       \
        const char* gp = psG + ((size_t)sg * 1000 + (c) * 64) * 32;             \
        char* lp = L + PS_BASE;                                                 \
        if (!(TAIL)) { gll16(gp + tid * 16, lp); gll16(gp + 1024 + tid * 16, lp + 1024); } \
        else         { gll16(gp + tid * 16, lp); gll4(gp + 1024 + tid * 4, lp + 1024); }   \
    } while (0)

#define COMPUTE(c, NSB) do {                                                    \
        const char* L = lds + ((c) & 1) * BUF_SZ;                               \
        const char* lk = L + sl * KM_STRIDE + h * 4;                            \
        const char* le = L + KE_BASE + sl * KE_STRIDE + h * 2;                  \
        const char* lp = L + PS_BASE + sl * 8;                                  \
        for (int sb = 0; sb < (NSB); ++sb) {                                    \
            unsigned int a[8]; ushort e[8]; float2 p[8];                        \
            _Pragma("unroll")                                                   \
            for (int i = 0; i < 8; ++i) {                                       \
                const int tt = sb * 8 + i;                                      \
                a[i] = *(const unsigned int*)(lk + tt * 64);                    \
                e[i] = *(const ushort*)(le + tt * 32);                          \
                p[i] = *(const float2*)(lp + tt * 32);                          \
            }                                                                   \
            float z[8];                                                         \
            _Pragma("unroll")                                                   \
            for (int i = 0; i < 8; ++i) {                                       \
                float km = __builtin_bit_cast(float, a[i] << 16);               \
                float ki = __builtin_bit_cast(float, a[i] & 0xffff0000u);       \
                float kev = __builtin_bit_cast(float, ((unsigned int)e[i]) << 16); \
                float ps = p[i].x, pl = p[i].y;                                 \
                Sf += ps;                                                       \
                float qf = fminf(Sf, km); Sf -= qf;                             \
                float inflow = qf + pl;                                         \
                float qd = inflow * gi;                                         \
                Ss = fmaf(inflow, gi1, Ss);                                     \
                float E = fminf(Ss, kev); Ss -= E;                              \
                float qi = fminf(ki, Ss); Ss -= qi;                             \
                float qp = kp * fmaxf(Ss - gl, 0.f);                            \
                float qsa = ks_ * fminf(Ss, gl);                                \
                Ss -= qp + qsa;                                                 \
                Sg = fmaf(qsa, gd, Sg);                                         \
                float qg = fmaf(kd, Sg, qbv);                                   \
                Sg *= kd1;                                                      \
                float q = fmaf(qsa, gd1, qp) + qg + qd + qi;                    \
                qh[i] = q;                                                      \
                float v = 0.f;                                                  \
                _Pragma("unroll")                                               \
                for (int k = 0; k < 8; ++k) v = fmaf(wrga[k], qh[(i - k) & 7], v); \
                z[i] = v;                                                       \
            }                                                                   \
            _Pragma("unroll")                                                   \
            for (int i = 0; i < 8; ++i) z[i] = dpp_add<0xB1>(z[i]);             \
            _Pragma("unroll")                                                   \
            for (int i = 0; i < 8; ++i) z[i] = dpp_add<0x4E>(z[i]);             \
            _Pragma("unroll")                                                   \
            for (int i = 0; i < 8; ++i) z[i] = dpp_add<0x141>(z[i]);            \
            _Pragma("unroll")                                                   \
            for (int i = 0; i < 8; ++i) z[i] = dpp_add<0x140>(z[i]);            \
            if (h == 0) {                                                       \
                _Pragma("unroll")                                               \
                for (int i = 0; i < 8; ++i) {                                   \
                    const int t = (c) * 64 + sb * 8 + i;                        \
                    if (t >= 7) yOut[(t - 7) * 2048 + s] = z[i];                \
                }                                                               \
            }                                                                   \
        }                                                                       \
    } while (0)

    STAGE(0, false);
    for (int c = 0; c < 16; ++c) {
        if (c < 15) {
            if (c + 1 == 15) STAGE(15, true);
            else             STAGE(c + 1, false);
            // chunk c's 26 DMAs retired once <=26 remain (those are chunk c+1's)
            asm volatile("s_waitcnt vmcnt(26)" ::: "memory");
        } else {
            asm volatile("s_waitcnt vmcnt(0)" ::: "memory");
        }
        if (c == 15) COMPUTE(15, 5);
        else         COMPUTE(c, 8);
        asm volatile("" ::: "memory");   // keep next STAGE below this compute
    }
#undef STAGE
#undef COMPUTE
}

// ---------------- launch ----------------
extern "C" void kernel_launch(void* const* d_in, const int* in_sizes, int n_in,
                              void* d_out, int out_size, void* d_ws, size_t ws_size,
                              hipStream_t stream) {
    const float* x      = (const float*)d_in[0];
    const float* xc     = (const float*)d_in[1];
    const float* W_fc   = (const float*)d_in[2];
    const float* b_fc   = (const float*)d_in[3];
    const float* W_r    = (const float*)d_in[4];
    const float* b_r    = (const float*)d_in[5];
    const float* W_g    = (const float*)d_in[6];
    const float* b_g    = (const float*)d_in[7];
    const float* W_kin  = (const float*)d_in[8];
    const float* b_kin  = (const float*)d_in[9];
    const float* W_kout = (const float*)d_in[10];
    const float* b_kout = (const float*)d_in[11];
    float* yOut = (float*)d_out;

    char* ws = (char*)d_ws;
    float*  stateK = (float*)(ws + 0);                        // 2 MB
    float*  params = (float*)(ws + (2 << 20));                // 19 planes (reserve 4 MB)
    ushort* Wt_g   = (ushort*)(ws + (6 << 20));               // 25,344 B
    ushort* whlo_g = (ushort*)(ws + (6 << 20) + (64 << 10));  // 4,096 B (within 128 KiB reserve)
    char*   p      = ws + (6 << 20) + (128 << 10);
    float2* pspl   = (float2*)p;                              // 16,384,000 B
    unsigned int* kmki = (unsigned int*)(p + 16384000);       // 131,072,000 B
    ushort* kevA   = (ushort*)(p + 16384000 + 131072000);     //  65,536,000 B
    // NOTE: kC tail staging reads up to ~1.5KB past kevA's end (t 1000..1023 of
    // site 2047 in the width-16 pattern) -- stays within typical ws slack; all
    // OOB accesses are reads into the same allocation region.

    hipLaunchKernelGGL(kA, dim3(2048), dim3(256), 0, stream,
                       xc, W_fc, b_fc, W_r, b_r, W_g, b_g, W_kin, b_kin, W_kout,
                       stateK, params, Wt_g, whlo_g);
    hipLaunchKernelGGL(kB, dim3(128 * 50), dim3(256), 0, stream,
                       x, stateK, b_kout, Wt_g, whlo_g, params, kmki, kevA, pspl);
    hipLaunchKernelGGL(kC, dim3(512), dim3(64), 0, stream,
                       kmki, kevA, pspl, params, yOut);
}

// Round 6
// 519.310 us; speedup vs baseline: 1.2250x; 1.0173x over previous
//
#include <hip/hip_runtime.h>
#include <hip/hip_bf16.h>

// Problem constants
#define NT   1000
#define NS   2048
#define NH   16
#define NR   8
#define HS   256
#define TOUT 993   // NT - NR + 1

typedef __attribute__((ext_vector_type(8))) short short8;
typedef __attribute__((ext_vector_type(4))) float f32x4;

__device__ __forceinline__ ushort f2bf(float f) {
    union { float f; unsigned int u; } v; v.f = f;
    unsigned int u = v.u;
    return (ushort)((u + 0x7fffu + ((u >> 16) & 1u)) >> 16);
}
__device__ __forceinline__ float bf2f(ushort u) {
    union { unsigned int i; float f; } v; v.i = ((unsigned int)u) << 16; return v.f;
}
__device__ __forceinline__ unsigned int packbf2(float lo, float hi) {
    union { __hip_bfloat162 b; unsigned int u; } v;
    v.b = __float22bfloat162_rn(make_float2(lo, hi));
    return v.u;
}
__device__ __forceinline__ float sigf(float x) { return 1.f / (1.f + __expf(-x)); }
__device__ __forceinline__ float fast_tanh(float z) {
    float e = exp2f(z * 2.885390082f);
    return 1.f - 2.f * __builtin_amdgcn_rcpf(e + 1.f);
}
template<int CTRL>
__device__ __forceinline__ float dpp_add(float v) {
    int s = __builtin_amdgcn_update_dpp(0, __builtin_bit_cast(int, v), CTRL, 0xf, 0xf, true);
    return v + __builtin_bit_cast(float, s);
}
// async global->LDS DMA: zero result VGPRs, counted by vmcnt.
__device__ __forceinline__ void gll16(const void* g, void* l) {
    __builtin_amdgcn_global_load_lds((const __attribute__((address_space(1))) unsigned int*)g,
                                     (__attribute__((address_space(3))) unsigned int*)l, 16, 0, 0);
}
__device__ __forceinline__ void gll4(const void* g, void* l) {
    __builtin_amdgcn_global_load_lds((const __attribute__((address_space(1))) unsigned int*)g,
                                     (__attribute__((address_space(3))) unsigned int*)l, 4, 0, 0);
}

// params planes: 0 kp, 1 ks, 2 kd, 3 gd, 4 gl, 5 qb, 6 gi, 7 1-gi, 8 1-kd,
//                9 1-gd, 10 ge, 11..18 wrga
// ---------------- Kernel A: per-site setup ----------------
__global__ __launch_bounds__(256) void kA(
    const float* __restrict__ xc, const float* __restrict__ W_fc, const float* __restrict__ b_fc,
    const float* __restrict__ W_r, const float* __restrict__ b_r,
    const float* __restrict__ W_g, const float* __restrict__ b_g,
    const float* __restrict__ W_kin, const float* __restrict__ b_kin,
    const float* __restrict__ W_kout,
    float* __restrict__ stateK, float* __restrict__ params,
    ushort* __restrict__ Wt_g, ushort* __restrict__ whlo_g)
{
    __shared__ float xcs[32];
    __shared__ float hG[256];
    __shared__ float pGR[288];
    const int s = blockIdx.x, tid = threadIdx.x;

    if (tid < 32) xcs[tid] = xc[s * 32 + tid];
    __syncthreads();

    float acc = b_fc[tid];
#pragma unroll 8
    for (int k = 0; k < 32; ++k) acc = fmaf(xcs[k], W_fc[k * 256 + tid], acc);
    stateK[s * 256 + tid] = acc + b_kin[tid];
    hG[tid] = tanhf(acc);
    __syncthreads();

    for (int j = tid; j < 288; j += 256) {
        const float* W = (j < 144) ? W_g : W_r;
        const float* b = (j < 144) ? b_g : b_r;
        int col = (j < 144) ? j : (j - 144);
        float a = b[col];
#pragma unroll 4
        for (int k = 0; k < 256; ++k) a = fmaf(hG[k], W[k * 144 + col], a);
        pGR[j] = a;
    }
    __syncthreads();

    if (tid < 16) {
        const int h = tid;
        float g0 = pGR[h],       g1 = pGR[16 + h],  g2 = pGR[32 + h];
        float g3 = pGR[48 + h],  g4 = pGR[64 + h],  g5 = pGR[80 + h];
        float g6 = pGR[96 + h],  g7 = pGR[112 + h], g8 = pGR[128 + h];
        float kp = sigf(g0), ksg = sigf(g1), kd = sigf(g2), gd = sigf(g3);
        float t4 = sigf(g4) * 10.f; float gl = t4 * t4 * t4;
        float qb = fmaxf(g5, 0.f) * 0.1f;
        float gi = fminf(fmaxf(g7 * (1.f / 6.f) + 0.5f, 0.f), 1.f) * 0.5f;
        float ge = fmaxf(g8, 0.f);
        float m = g6;
        for (int o = 1; o < 16; o <<= 1) m = fmaxf(m, __shfl_xor(m, o));
        float e = __expf(g6 - m), esum = e;
        for (int o = 1; o < 16; o <<= 1) esum += __shfl_xor(esum, o);
        float ga = e / esum;
        float r[9], rm = -1e30f;
#pragma unroll
        for (int i = 0; i < 9; ++i) { r[i] = pGR[144 + h * 9 + i]; rm = fmaxf(rm, r[i]); }
        float er[9], es = 0.f;
#pragma unroll
        for (int i = 0; i < 9; ++i) { er[i] = __expf(r[i] - rm); es += er[i]; }
        float inv_es = 1.f / es, c = 0.f, wsum = 0.f, w[8];
#pragma unroll
        for (int i = 0; i < 8; ++i) {
            float si = er[i] * inv_es; c += si;
            float wi = fminf(c, 1.f - c + si);
            w[i] = wi; wsum += wi;
        }
        const int base = s * 16 + h;
        params[0 * 32768 + base] = kp;       params[1 * 32768 + base] = ksg;
        params[2 * 32768 + base] = kd;       params[3 * 32768 + base] = gd;
        params[4 * 32768 + base] = gl;       params[5 * 32768 + base] = qb;
        params[6 * 32768 + base] = gi;       params[7 * 32768 + base] = 1.f - gi;
        params[8 * 32768 + base] = 1.f - kd; params[9 * 32768 + base] = 1.f - gd;
        params[10 * 32768 + base] = ge;
        float sc = ga / wsum;
#pragma unroll
        for (int i = 0; i < 8; ++i) params[(11 + i) * 32768 + base] = w[i] * sc;
    }

    if (s == 0) {
        // Wt_g: W_kout^T in bf16, stride 264, rows permuted to match the
        // first-MFMA D layout (see kB).
        for (int i = tid; i < 48 * 256; i += 256) {
            int col = i % 48, slot = i / 48;
            int kk = slot >> 5, q = (slot >> 3) & 3, j = slot & 7;
            int h = kk * 32 + ((j < 4) ? (q * 4 + j) : (16 + q * 4 + (j - 4)));
            Wt_g[col * 264 + slot] = f2bf(W_kout[h * 48 + col]);
        }
        // whlo_g[h*8 + f] = bf16 hi of W_kin[f][h]; +4: lo residual
        {
            const int h = tid;
#pragma unroll
            for (int f = 0; f < 4; ++f) {
                float w = W_kin[f * 256 + h];
                ushort hi = f2bf(w);
                float lo = w - bf2f(hi);
                whlo_g[h * 8 + f] = hi;
                whlo_g[h * 8 + 4 + f] = f2bf(lo);
            }
        }
    }
}

// ---------------- Kernel B v11 (unchanged, measured 261us) ----------------
__global__ __launch_bounds__(256, 3) void kB(
    const float* __restrict__ x,
    const float* __restrict__ stateK, const float* __restrict__ b_kout,
    const ushort* __restrict__ Wt_g, const ushort* __restrict__ whlo_g,
    const float* __restrict__ params,
    unsigned int* __restrict__ kmki, ushort* __restrict__ kevA,
    float2* __restrict__ pspl)
{
    __shared__ ushort Wt[48 * 264];    // 25,344 B
    __shared__ float  stS[16 * 260];   // 16,640 B
    __shared__ ushort whloS[2048];     //  4,096 B  [hidden][8: wh0..3, wl0..3]
    __shared__ float  geS[256];        //  1,024 B  [site_local*16 + h]
    __shared__ float  evS[4][5][16];   //  1,280 B  [wave][ti][site_local]
    const int tid = threadIdx.x;
    const int st = blockIdx.x & 127;   // site tile (0..127)
    const int tg = blockIdx.x >> 7;    // t group (0..49)
    const int s0 = st << 4;

    for (int i = tid; i < 3168; i += 256)
        ((uint2*)Wt)[i] = ((const uint2*)Wt_g)[i];
#pragma unroll
    for (int i = tid; i < 1024; i += 256) {
        int row = i >> 6, c = (i & 63) << 2;
        *(float4*)(stS + row * 260 + c) = *(const float4*)(stateK + (s0 + row) * 256 + c);
    }
    *(float4*)(whloS + tid * 8) = ((const float4*)whlo_g)[tid];
    geS[tid] = params[10 * 32768 + s0 * 16 + tid];
    __syncthreads();

    const int wv = tid >> 6, lane = tid & 63;
    const int mi = lane & 15, quad = lane >> 4;
    const int site = s0 + mi;
    const int t0 = tg * 20 + wv * 5;   // 50*20 = 1000, guard-free

    float xf[5][4];
#pragma unroll
    for (int ti = 0; ti < 5; ++ti) {
        const int t = t0 + ti;
        const int xb = (t * 2048 + site) * 6;
        float2 u23 = *(const float2*)(x + xb + 2);
        float2 u45 = *(const float2*)(x + xb + 4);
        xf[ti][0] = u23.x; xf[ti][1] = u23.y; xf[ti][2] = u45.x; xf[ti][3] = u45.y;
        if (lane < 16) {   // quad 0: ps/pl in [sg][t][sl] layout, ev tile in LDS
            float2 u01 = *(const float2*)(x + xb);
            float fl = fminf(fmaxf(u23.y * __builtin_amdgcn_rcpf(u23.y - u23.x + 1e-5f), 0.f), 1.f);
            const int sg = st * 4 + (mi >> 2), sl = mi & 3;
            pspl[(sg * 1000 + t) * 4 + sl] = make_float2(u01.x * (1.f - fl), u01.x * fl);
            evS[wv][ti][mi] = u01.y;
        }
    }

    unsigned int bfr[5][4];
#pragma unroll
    for (int ti = 0; ti < 5; ++ti) {
        const float x0 = xf[ti][0], x1 = xf[ti][1], x2 = xf[ti][2], x3 = xf[ti][3];
        unsigned int h01 = packbf2(x0, x1), h23 = packbf2(x2, x3);
        float l0 = x0 - bf2f((ushort)(h01 & 0xffffu));
        float l1 = x1 - bf2f((ushort)(h01 >> 16));
        float l2 = x2 - bf2f((ushort)(h23 & 0xffffu));
        float l3 = x3 - bf2f((ushort)(h23 >> 16));
        unsigned int l01 = packbf2(l0, l1), l23 = packbf2(l2, l3);
        bfr[ti][0] = (quad == 0) ? h01 : (quad == 1 ? l01 : 0u);
        bfr[ti][1] = (quad == 0) ? h23 : (quad == 1 ? l23 : 0u);
        bfr[ti][2] = (quad == 0) ? h01 : 0u;
        bfr[ti][3] = (quad == 0) ? h23 : 0u;
    }

    const float*  stp = stS + mi * 260;
    const ushort* Wt0 = Wt + mi * 264 + quad * 8;
    const int q4 = quad * 4;

    f32x4 acc[5][3];
#pragma unroll
    for (int ti = 0; ti < 5; ++ti)
#pragma unroll
        for (int j = 0; j < 3; ++j) acc[ti][j] = (f32x4){0.f, 0.f, 0.f, 0.f};

#pragma unroll 1
    for (int kk = 0; kk < 8; ++kk) {
        const int ko = kk * 32;
        union { short8 s; unsigned int u[4]; } W0, W1, A0, A1;
        W0.s = *(const short8*)(whloS + (ko + mi) * 8);
        W1.s = *(const short8*)(whloS + (ko + 16 + mi) * 8);
        A0.u[0] = (quad <= 1) ? W0.u[0] : 0u;
        A0.u[1] = (quad <= 1) ? W0.u[1] : 0u;
        A0.u[2] = (quad == 0) ? W0.u[2] : 0u;
        A0.u[3] = (quad == 0) ? W0.u[3] : 0u;
        A1.u[0] = (quad <= 1) ? W1.u[0] : 0u;
        A1.u[1] = (quad <= 1) ? W1.u[1] : 0u;
        A1.u[2] = (quad == 0) ? W1.u[2] : 0u;
        A1.u[3] = (quad == 0) ? W1.u[3] : 0u;
        f32x4 c0 = *(const f32x4*)(stp + ko + q4);
        f32x4 c1 = *(const f32x4*)(stp + ko + 16 + q4);
        short8 b0 = *(const short8*)(Wt0 + ko);
        short8 b1 = *(const short8*)(Wt0 + 16 * 264 + ko);
        short8 b2 = *(const short8*)(Wt0 + 32 * 264 + ko);
#pragma unroll
        for (int ti = 0; ti < 5; ++ti) {
            union { short8 s; unsigned int u[4]; } B;
            B.u[0] = bfr[ti][0]; B.u[1] = bfr[ti][1];
            B.u[2] = bfr[ti][2]; B.u[3] = bfr[ti][3];
            f32x4 z0 = __builtin_amdgcn_mfma_f32_16x16x32_bf16(A0.s, B.s, c0, 0, 0, 0);
            f32x4 z1 = __builtin_amdgcn_mfma_f32_16x16x32_bf16(A1.s, B.s, c1, 0, 0, 0);
            union { short8 s; unsigned int u[4]; } a;
            a.u[0] = packbf2(fast_tanh(z0[0]), fast_tanh(z0[1]));
            a.u[1] = packbf2(fast_tanh(z0[2]), fast_tanh(z0[3]));
            a.u[2] = packbf2(fast_tanh(z1[0]), fast_tanh(z1[1]));
            a.u[3] = packbf2(fast_tanh(z1[2]), fast_tanh(z1[3]));
            acc[ti][0] = __builtin_amdgcn_mfma_f32_16x16x32_bf16(a.s, b0, acc[ti][0], 0, 0, 0);
            acc[ti][1] = __builtin_amdgcn_mfma_f32_16x16x32_bf16(a.s, b1, acc[ti][1], 0, 0, 0);
            acc[ti][2] = __builtin_amdgcn_mfma_f32_16x16x32_bf16(a.s, b2, acc[ti][2], 0, 0, 0);
        }
    }

    // epilogue: kmki/kevA[site][t][h]
    const float bo0 = b_kout[mi], bo1 = b_kout[16 + mi], bo2 = b_kout[32 + mi];
#pragma unroll
    for (int ti = 0; ti < 5; ++ti) {
        const int t = t0 + ti;
#pragma unroll
        for (int reg = 0; reg < 4; ++reg) {
            const int sl = quad * 4 + reg;
            float km = __expf(acc[ti][0][reg] + bo0);
            float ki = fmaxf(acc[ti][1][reg] + bo1, 0.f);
            float ke = __expf(acc[ti][2][reg] + bo2);
            float kev = ke * evS[wv][ti][sl] * geS[sl * 16 + mi];
            const int idx = ((s0 + sl) * 1000 + t) * 16 + mi;
            kmki[idx] = (unsigned int)f2bf(km) | ((unsigned int)f2bf(ki) << 16);
            kevA[idx] = f2bf(kev);
        }
    }
}

// ---------------- Kernel C v12: DMA staging + lagged-conv software pipeline ----------------
// r4 post-mortem: two different kC structures both ~230us (552 cy/t vs ~110 cy/t issue
// floor) -> fill-factor ~0.2 at 1 wave/SIMD. Cause: conv(b) depends on scan(b), so the
// only ready work at any moment is the next link of a dependence chain.
// Fix: lag the conv one batch. conv(b-1) is INDEPENDENT of scan(b)'s serial chain;
// emit [scan(b) || conv+dpp+store(b-1)] branch-free so the scheduler fills scan's
// stall slots with ~140 independent instructions. Batch -1 conv is computed as
// garbage and suppressed by the existing t>=7 store guard (no branch walls).
// (Resubmission of r5: bench infra failed twice, kernel never measured.)
#define KM_STRIDE 4160   // 4096 + 64 pad
#define KE_BASE   16640  // 4*4160
#define KE_STRIDE 2080   // 2048 + 32 pad
#define PS_BASE   24960  // 16640 + 4*2080
#define BUF_SZ    27008  // 24960 + 2048
__global__ __launch_bounds__(64, 1) void kC(
    const unsigned int* __restrict__ kmki, const ushort* __restrict__ kevA,
    const float2* __restrict__ pspl,
    const float* __restrict__ params, float* __restrict__ yOut)
{
    __shared__ char lds[2 * BUF_SZ];   // 54,016 B
    const int tid = threadIdx.x;
    const int sg = blockIdx.x;              // s_group (4 sites per wave)
    const int sl = tid >> 4;
    const int s = sg * 4 + sl;
    const int h = tid & 15;
    const int gid = s * 16 + h;

    const float kp  = params[0 * 32768 + gid];
    const float ks_ = params[1 * 32768 + gid];
    const float kd  = params[2 * 32768 + gid];
    const float gd  = params[3 * 32768 + gid];
    const float gl  = params[4 * 32768 + gid];
    const float qbv = params[5 * 32768 + gid];
    const float gi  = params[6 * 32768 + gid];
    const float gi1 = params[7 * 32768 + gid];
    const float kd1 = params[8 * 32768 + gid];
    const float gd1 = params[9 * 32768 + gid];
    float wrga[8];
#pragma unroll
    for (int i = 0; i < 8; ++i) wrga[i] = params[(11 + i) * 32768 + gid];

    float Sf = 0.f, Ss = 0.f, Sg = 0.f;
    float qcur[8], qp1[8], qp2[8];
#pragma unroll
    for (int i = 0; i < 8; ++i) { qcur[i] = 0.f; qp1[i] = 0.f; qp2[i] = 0.f; }

    const char* kmG = (const char*)kmki;   // [site][t][h] uint   -> 64 B/t/site
    const char* keG = (const char*)kevA;   // [site][t][h] ushort -> 32 B/t/site
    const char* psG = (const char*)pspl;   // [sg][t][sl] float2  -> 32 B/t

#define STAGE(c, TAIL) do {                                                     \
        char* L = lds + ((c) & 1) * BUF_SZ;                                     \
        _Pragma("unroll")                                                       \
        for (int q = 0; q < 4; ++q) {                                           \
            const char* gk = kmG + ((size_t)(sg * 4 + q) * 1000 + (c) * 64) * 64; \
            const char* ge = keG + ((size_t)(sg * 4 + q) * 1000 + (c) * 64) * 32; \
            char* lk = L + q * KM_STRIDE;                                       \
            char* le = L + KE_BASE + q * KE_STRIDE;                             \
            if (!(TAIL)) {                                                      \
                _Pragma("unroll")                                               \
                for (int k = 0; k < 4; ++k) gll16(gk + k * 1024 + tid * 16, lk + k * 1024); \
                _Pragma("unroll")                                               \
                for (int k = 0; k < 2; ++k) gll16(ge + k * 1024 + tid * 16, le + k * 1024); \
            } else {                                                            \
                _Pragma("unroll")                                               \
                for (int k = 0; k < 2; ++k) gll16(gk + k * 1024 + tid * 16, lk + k * 1024); \
                _Pragma("unroll")                                               \
                for (int k = 0; k < 2; ++k) gll4(gk + 2048 + k * 256 + tid * 4, lk + 2048 + k * 256); \
                gll16(ge + tid * 16, le);                                       \
                gll4(ge + 1024 + tid * 4, le + 1024);                           \
            }                                                                   \
        }                                                                       \
        const char* gp = psG + ((size_t)sg * 1000 + (c) * 64) * 32;             \
        char* lp = L + PS_BASE;                                                 \
        if (!(TAIL)) { gll16(gp + tid * 16, lp); gll16(gp + 1024 + tid * 16, lp + 1024); } \
        else         { gll16(gp + tid * 16, lp); gll4(gp + 1024 + tid * 4, lp + 1024); }   \
    } while (0)

    // scan batch (c, sb): fills qcur[0..7] from LDS buffer c&1
#define SCANB(c, sb) do {                                                       \
        const char* L = lds + ((c) & 1) * BUF_SZ;                               \
        const char* lk = L + sl * KM_STRIDE + h * 4 + (sb) * 512;               \
        const char* le = L + KE_BASE + sl * KE_STRIDE + h * 2 + (sb) * 256;     \
        const char* lp = L + PS_BASE + sl * 8 + (sb) * 256;                     \
        unsigned int a[8]; ushort e[8]; float2 p[8];                            \
        _Pragma("unroll")                                                       \
        for (int i = 0; i < 8; ++i) {                                           \
            a[i] = *(const unsigned int*)(lk + i * 64);                         \
            e[i] = *(const ushort*)(le + i * 32);                               \
            p[i] = *(const float2*)(lp + i * 32);                               \
        }                                                                       \
        _Pragma("unroll")                                                       \
        for (int i = 0; i < 8; ++i) {                                           \
            float km = __builtin_bit_cast(float, a[i] << 16);                   \
            float ki = __builtin_bit_cast(float, a[i] & 0xffff0000u);           \
            float kev = __builtin_bit_cast(float, ((unsigned int)e[i]) << 16);  \
            float ps = p[i].x, pl = p[i].y;                                     \
            Sf += ps;                                                           \
            float qf = fminf(Sf, km); Sf -= qf;                                 \
            float inflow = qf + pl;                                             \
            float qd = inflow * gi;                                             \
            Ss = fmaf(inflow, gi1, Ss);                                         \
            float E = fminf(Ss, kev); Ss -= E;                                  \
            float qi = fminf(ki, Ss); Ss -= qi;                                 \
            float qp = kp * fmaxf(Ss - gl, 0.f);                                \
            float qsa = ks_ * fminf(Ss, gl);                                    \
            Ss -= qp + qsa;                                                     \
            Sg = fmaf(qsa, gd, Sg);                                             \
            float qg = fmaf(kd, Sg, qbv);                                       \
            Sg *= kd1;                                                          \
            qcur[i] = fmaf(qsa, gd1, qp) + qg + qd + qi;                        \
        }                                                                       \
    } while (0)

    // conv + 16-lane reduce + store for batch m (uses qp1=q_m, qp2=q_{m-1});
    // m may be -1 or 0: the t>=7 guard suppresses invalid stores.
#define CONV_STORE(m) do {                                                      \
        float z[8];                                                             \
        _Pragma("unroll")                                                       \
        for (int i = 0; i < 8; ++i) {                                           \
            float za = wrga[6] * ((i >= 6) ? qp1[i - 6] : qp2[i + 2]);          \
            za = fmaf(wrga[4], (i >= 4) ? qp1[i - 4] : qp2[i + 4], za);         \
            za = fmaf(wrga[2], (i >= 2) ? qp1[i - 2] : qp2[i + 6], za);         \
            za = fmaf(wrga[0], qp1[i], za);                                     \
            float zb = wrga[7] * ((i >= 7) ? qp1[i - 7] : qp2[i + 1]);          \
            zb = fmaf(wrga[5], (i >= 5) ? qp1[i - 5] : qp2[i + 3], zb);         \
            zb = fmaf(wrga[3], (i >= 3) ? qp1[i - 3] : qp2[i + 5], zb);         \
            zb = fmaf(wrga[1], (i >= 1) ? qp1[i - 1] : qp2[i + 7], zb);         \
            z[i] = za + zb;                                                     \
        }                                                                       \
        _Pragma("unroll")                                                       \
        for (int i = 0; i < 8; ++i) z[i] = dpp_add<0xB1>(z[i]);                 \
        _Pragma("unroll")                                                       \
        for (int i = 0; i < 8; ++i) z[i] = dpp_add<0x4E>(z[i]);                 \
        _Pragma("unroll")                                                       \
        for (int i = 0; i < 8; ++i) z[i] = dpp_add<0x141>(z[i]);                \
        _Pragma("unroll")                                                       \
        for (int i = 0; i < 8; ++i) z[i] = dpp_add<0x140>(z[i]);                \
        if (h == 0) {                                                           \
            _Pragma("unroll")                                                   \
            for (int i = 0; i < 8; ++i) {                                       \
                const int t = (m) * 8 + i;                                      \
                if (t >= 7) yOut[(t - 7) * 2048 + s] = z[i];                    \
            }                                                                   \
        }                                                                       \
    } while (0)

    STAGE(0, false);
    int g = 0;
#pragma unroll 1
    for (int c = 0; c < 16; ++c) {
        if (c < 15) {
            if (c + 1 == 15) STAGE(15, true);
            else             STAGE(c + 1, false);
            asm volatile("s_waitcnt vmcnt(26)" ::: "memory");
        } else {
            asm volatile("s_waitcnt vmcnt(0)" ::: "memory");
        }
        const int NSB = (c == 15) ? 5 : 8;
#pragma unroll 1
        for (int sb = 0; sb < NSB; ++sb, ++g) {
            SCANB(c, sb);          // serial-chain work for batch g
            CONV_STORE(g - 1);     // independent filler: batch g-1
#pragma unroll
            for (int i = 0; i < 8; ++i) { qp2[i] = qp1[i]; qp1[i] = qcur[i]; }
        }
        asm volatile("" ::: "memory");
    }
    CONV_STORE(124);               // drain last batch (qp1 = q_124 after final rotate)
#undef STAGE
#undef SCANB
#undef CONV_STORE
}

// ---------------- launch ----------------
extern "C" void kernel_launch(void* const* d_in, const int* in_sizes, int n_in,
                              void* d_out, int out_size, void* d_ws, size_t ws_size,
                              hipStream_t stream) {
    const float* x      = (const float*)d_in[0];
    const float* xc     = (const float*)d_in[1];
    const float* W_fc   = (const float*)d_in[2];
    const float* b_fc   = (const float*)d_in[3];
    const float* W_r    = (const float*)d_in[4];
    const float* b_r    = (const float*)d_in[5];
    const float* W_g    = (const float*)d_in[6];
    const float* b_g    = (const float*)d_in[7];
    const float* W_kin  = (const float*)d_in[8];
    const float* b_kin  = (const float*)d_in[9];
    const float* W_kout = (const float*)d_in[10];
    const float* b_kout = (const float*)d_in[11];
    float* yOut = (float*)d_out;

    char* ws = (char*)d_ws;
    float*  stateK = (float*)(ws + 0);                        // 2 MB
    float*  params = (float*)(ws + (2 << 20));                // 19 planes (reserve 4 MB)
    ushort* Wt_g   = (ushort*)(ws + (6 << 20));               // 25,344 B
    ushort* whlo_g = (ushort*)(ws + (6 << 20) + (64 << 10));  // 4,096 B
    char*   p      = ws + (6 << 20) + (128 << 10);
    float2* pspl   = (float2*)p;                              // 16,384,000 B
    unsigned int* kmki = (unsigned int*)(p + 16384000);       // 131,072,000 B
    ushort* kevA   = (ushort*)(p + 16384000 + 131072000);     //  65,536,000 B

    hipLaunchKernelGGL(kA, dim3(2048), dim3(256), 0, stream,
                       xc, W_fc, b_fc, W_r, b_r, W_g, b_g, W_kin, b_kin, W_kout,
                       stateK, params, Wt_g, whlo_g);
    hipLaunchKernelGGL(kB, dim3(128 * 50), dim3(256), 0, stream,
                       x, stateK, b_kout, Wt_g, whlo_g, params, kmki, kevA, pspl);
    hipLaunchKernelGGL(kC, dim3(512), dim3(64), 0, stream,
                       kmki, kevA, pspl, params, yOut);
}

// Round 7
// 517.151 us; speedup vs baseline: 1.2301x; 1.0042x over previous
//
#include <hip/hip_runtime.h>
#include <hip/hip_bf16.h>

// Problem constants
#define NT   1000
#define NS   2048
#define NH   16
#define NR   8
#define HS   256
#define TOUT 993   // NT - NR + 1

typedef __attribute__((ext_vector_type(8))) short short8;
typedef __attribute__((ext_vector_type(4))) float f32x4;

__device__ __forceinline__ ushort f2bf(float f) {
    union { float f; unsigned int u; } v; v.f = f;
    unsigned int u = v.u;
    return (ushort)((u + 0x7fffu + ((u >> 16) & 1u)) >> 16);
}
__device__ __forceinline__ float bf2f(ushort u) {
    union { unsigned int i; float f; } v; v.i = ((unsigned int)u) << 16; return v.f;
}
__device__ __forceinline__ unsigned int packbf2(float lo, float hi) {
    union { __hip_bfloat162 b; unsigned int u; } v;
    v.b = __float22bfloat162_rn(make_float2(lo, hi));
    return v.u;
}
__device__ __forceinline__ float sigf(float x) { return 1.f / (1.f + __expf(-x)); }
__device__ __forceinline__ float fast_tanh(float z) {
    float e = exp2f(z * 2.885390082f);
    return 1.f - 2.f * __builtin_amdgcn_rcpf(e + 1.f);
}
template<int CTRL>
__device__ __forceinline__ float dpp_add(float v) {
    int s = __builtin_amdgcn_update_dpp(0, __builtin_bit_cast(int, v), CTRL, 0xf, 0xf, true);
    return v + __builtin_bit_cast(float, s);
}
// async global->LDS DMA: zero result VGPRs, counted by vmcnt.
__device__ __forceinline__ void gll16(const void* g, void* l) {
    __builtin_amdgcn_global_load_lds((const __attribute__((address_space(1))) unsigned int*)g,
                                     (__attribute__((address_space(3))) unsigned int*)l, 16, 0, 0);
}
__device__ __forceinline__ void gll4(const void* g, void* l) {
    __builtin_amdgcn_global_load_lds((const __attribute__((address_space(1))) unsigned int*)g,
                                     (__attribute__((address_space(3))) unsigned int*)l, 4, 0, 0);
}

// params planes: 0 kp, 1 ks, 2 kd, 3 gd, 4 gl, 5 qb, 6 gi, 7 1-gi, 8 1-kd,
//                9 1-gd, 10 ge, 11..18 wrga
// ---------------- Kernel A: per-site setup ----------------
__global__ __launch_bounds__(256) void kA(
    const float* __restrict__ xc, const float* __restrict__ W_fc, const float* __restrict__ b_fc,
    const float* __restrict__ W_r, const float* __restrict__ b_r,
    const float* __restrict__ W_g, const float* __restrict__ b_g,
    const float* __restrict__ W_kin, const float* __restrict__ b_kin,
    const float* __restrict__ W_kout,
    float* __restrict__ stateK, float* __restrict__ params,
    ushort* __restrict__ Wt_g, ushort* __restrict__ whlo_g)
{
    __shared__ float xcs[32];
    __shared__ float hG[256];
    __shared__ float pGR[288];
    const int s = blockIdx.x, tid = threadIdx.x;

    if (tid < 32) xcs[tid] = xc[s * 32 + tid];
    __syncthreads();

    float acc = b_fc[tid];
#pragma unroll 8
    for (int k = 0; k < 32; ++k) acc = fmaf(xcs[k], W_fc[k * 256 + tid], acc);
    stateK[s * 256 + tid] = acc + b_kin[tid];
    hG[tid] = tanhf(acc);
    __syncthreads();

    for (int j = tid; j < 288; j += 256) {
        const float* W = (j < 144) ? W_g : W_r;
        const float* b = (j < 144) ? b_g : b_r;
        int col = (j < 144) ? j : (j - 144);
        float a = b[col];
#pragma unroll 4
        for (int k = 0; k < 256; ++k) a = fmaf(hG[k], W[k * 144 + col], a);
        pGR[j] = a;
    }
    __syncthreads();

    if (tid < 16) {
        const int h = tid;
        float g0 = pGR[h],       g1 = pGR[16 + h],  g2 = pGR[32 + h];
        float g3 = pGR[48 + h],  g4 = pGR[64 + h],  g5 = pGR[80 + h];
        float g6 = pGR[96 + h],  g7 = pGR[112 + h], g8 = pGR[128 + h];
        float kp = sigf(g0), ksg = sigf(g1), kd = sigf(g2), gd = sigf(g3);
        float t4 = sigf(g4) * 10.f; float gl = t4 * t4 * t4;
        float qb = fmaxf(g5, 0.f) * 0.1f;
        float gi = fminf(fmaxf(g7 * (1.f / 6.f) + 0.5f, 0.f), 1.f) * 0.5f;
        float ge = fmaxf(g8, 0.f);
        float m = g6;
        for (int o = 1; o < 16; o <<= 1) m = fmaxf(m, __shfl_xor(m, o));
        float e = __expf(g6 - m), esum = e;
        for (int o = 1; o < 16; o <<= 1) esum += __shfl_xor(esum, o);
        float ga = e / esum;
        float r[9], rm = -1e30f;
#pragma unroll
        for (int i = 0; i < 9; ++i) { r[i] = pGR[144 + h * 9 + i]; rm = fmaxf(rm, r[i]); }
        float er[9], es = 0.f;
#pragma unroll
        for (int i = 0; i < 9; ++i) { er[i] = __expf(r[i] - rm); es += er[i]; }
        float inv_es = 1.f / es, c = 0.f, wsum = 0.f, w[8];
#pragma unroll
        for (int i = 0; i < 8; ++i) {
            float si = er[i] * inv_es; c += si;
            float wi = fminf(c, 1.f - c + si);
            w[i] = wi; wsum += wi;
        }
        const int base = s * 16 + h;
        params[0 * 32768 + base] = kp;       params[1 * 32768 + base] = ksg;
        params[2 * 32768 + base] = kd;       params[3 * 32768 + base] = gd;
        params[4 * 32768 + base] = gl;       params[5 * 32768 + base] = qb;
        params[6 * 32768 + base] = gi;       params[7 * 32768 + base] = 1.f - gi;
        params[8 * 32768 + base] = 1.f - kd; params[9 * 32768 + base] = 1.f - gd;
        params[10 * 32768 + base] = ge;
        float sc = ga / wsum;
#pragma unroll
        for (int i = 0; i < 8; ++i) params[(11 + i) * 32768 + base] = w[i] * sc;
    }

    if (s == 0) {
        // Wt_g: W_kout^T in bf16, stride 264, rows permuted to match the
        // first-MFMA D layout (see kB).
        for (int i = tid; i < 48 * 256; i += 256) {
            int col = i % 48, slot = i / 48;
            int kk = slot >> 5, q = (slot >> 3) & 3, j = slot & 7;
            int h = kk * 32 + ((j < 4) ? (q * 4 + j) : (16 + q * 4 + (j - 4)));
            Wt_g[col * 264 + slot] = f2bf(W_kout[h * 48 + col]);
        }
        // whlo_g[h*8 + f] = bf16 hi of W_kin[f][h]; +4: lo residual
        {
            const int h = tid;
#pragma unroll
            for (int f = 0; f < 4; ++f) {
                float w = W_kin[f * 256 + h];
                ushort hi = f2bf(w);
                float lo = w - bf2f(hi);
                whlo_g[h * 8 + f] = hi;
                whlo_g[h * 8 + 4 + f] = f2bf(lo);
            }
        }
    }
}

// ---------------- Kernel B v11 (unchanged, measured 261us) ----------------
__global__ __launch_bounds__(256, 3) void kB(
    const float* __restrict__ x,
    const float* __restrict__ stateK, const float* __restrict__ b_kout,
    const ushort* __restrict__ Wt_g, const ushort* __restrict__ whlo_g,
    const float* __restrict__ params,
    unsigned int* __restrict__ kmki, ushort* __restrict__ kevA,
    float2* __restrict__ pspl)
{
    __shared__ ushort Wt[48 * 264];    // 25,344 B
    __shared__ float  stS[16 * 260];   // 16,640 B
    __shared__ ushort whloS[2048];     //  4,096 B  [hidden][8: wh0..3, wl0..3]
    __shared__ float  geS[256];        //  1,024 B  [site_local*16 + h]
    __shared__ float  evS[4][5][16];   //  1,280 B  [wave][ti][site_local]
    const int tid = threadIdx.x;
    const int st = blockIdx.x & 127;   // site tile (0..127)
    const int tg = blockIdx.x >> 7;    // t group (0..49)
    const int s0 = st << 4;

    for (int i = tid; i < 3168; i += 256)
        ((uint2*)Wt)[i] = ((const uint2*)Wt_g)[i];
#pragma unroll
    for (int i = tid; i < 1024; i += 256) {
        int row = i >> 6, c = (i & 63) << 2;
        *(float4*)(stS + row * 260 + c) = *(const float4*)(stateK + (s0 + row) * 256 + c);
    }
    *(float4*)(whloS + tid * 8) = ((const float4*)whlo_g)[tid];
    geS[tid] = params[10 * 32768 + s0 * 16 + tid];
    __syncthreads();

    const int wv = tid >> 6, lane = tid & 63;
    const int mi = lane & 15, quad = lane >> 4;
    const int site = s0 + mi;
    const int t0 = tg * 20 + wv * 5;   // 50*20 = 1000, guard-free

    float xf[5][4];
#pragma unroll
    for (int ti = 0; ti < 5; ++ti) {
        const int t = t0 + ti;
        const int xb = (t * 2048 + site) * 6;
        float2 u23 = *(const float2*)(x + xb + 2);
        float2 u45 = *(const float2*)(x + xb + 4);
        xf[ti][0] = u23.x; xf[ti][1] = u23.y; xf[ti][2] = u45.x; xf[ti][3] = u45.y;
        if (lane < 16) {   // quad 0: ps/pl in [sg][t][sl] layout, ev tile in LDS
            float2 u01 = *(const float2*)(x + xb);
            float fl = fminf(fmaxf(u23.y * __builtin_amdgcn_rcpf(u23.y - u23.x + 1e-5f), 0.f), 1.f);
            const int sg = st * 4 + (mi >> 2), sl = mi & 3;
            pspl[(sg * 1000 + t) * 4 + sl] = make_float2(u01.x * (1.f - fl), u01.x * fl);
            evS[wv][ti][mi] = u01.y;
        }
    }

    unsigned int bfr[5][4];
#pragma unroll
    for (int ti = 0; ti < 5; ++ti) {
        const float x0 = xf[ti][0], x1 = xf[ti][1], x2 = xf[ti][2], x3 = xf[ti][3];
        unsigned int h01 = packbf2(x0, x1), h23 = packbf2(x2, x3);
        float l0 = x0 - bf2f((ushort)(h01 & 0xffffu));
        float l1 = x1 - bf2f((ushort)(h01 >> 16));
        float l2 = x2 - bf2f((ushort)(h23 & 0xffffu));
        float l3 = x3 - bf2f((ushort)(h23 >> 16));
        unsigned int l01 = packbf2(l0, l1), l23 = packbf2(l2, l3);
        bfr[ti][0] = (quad == 0) ? h01 : (quad == 1 ? l01 : 0u);
        bfr[ti][1] = (quad == 0) ? h23 : (quad == 1 ? l23 : 0u);
        bfr[ti][2] = (quad == 0) ? h01 : 0u;
        bfr[ti][3] = (quad == 0) ? h23 : 0u;
    }

    const float*  stp = stS + mi * 260;
    const ushort* Wt0 = Wt + mi * 264 + quad * 8;
    const int q4 = quad * 4;

    f32x4 acc[5][3];
#pragma unroll
    for (int ti = 0; ti < 5; ++ti)
#pragma unroll
        for (int j = 0; j < 3; ++j) acc[ti][j] = (f32x4){0.f, 0.f, 0.f, 0.f};

#pragma unroll 1
    for (int kk = 0; kk < 8; ++kk) {
        const int ko = kk * 32;
        union { short8 s; unsigned int u[4]; } W0, W1, A0, A1;
        W0.s = *(const short8*)(whloS + (ko + mi) * 8);
        W1.s = *(const short8*)(whloS + (ko + 16 + mi) * 8);
        A0.u[0] = (quad <= 1) ? W0.u[0] : 0u;
        A0.u[1] = (quad <= 1) ? W0.u[1] : 0u;
        A0.u[2] = (quad == 0) ? W0.u[2] : 0u;
        A0.u[3] = (quad == 0) ? W0.u[3] : 0u;
        A1.u[0] = (quad <= 1) ? W1.u[0] : 0u;
        A1.u[1] = (quad <= 1) ? W1.u[1] : 0u;
        A1.u[2] = (quad == 0) ? W1.u[2] : 0u;
        A1.u[3] = (quad == 0) ? W1.u[3] : 0u;
        f32x4 c0 = *(const f32x4*)(stp + ko + q4);
        f32x4 c1 = *(const f32x4*)(stp + ko + 16 + q4);
        short8 b0 = *(const short8*)(Wt0 + ko);
        short8 b1 = *(const short8*)(Wt0 + 16 * 264 + ko);
        short8 b2 = *(const short8*)(Wt0 + 32 * 264 + ko);
#pragma unroll
        for (int ti = 0; ti < 5; ++ti) {
            union { short8 s; unsigned int u[4]; } B;
            B.u[0] = bfr[ti][0]; B.u[1] = bfr[ti][1];
            B.u[2] = bfr[ti][2]; B.u[3] = bfr[ti][3];
            f32x4 z0 = __builtin_amdgcn_mfma_f32_16x16x32_bf16(A0.s, B.s, c0, 0, 0, 0);
            f32x4 z1 = __builtin_amdgcn_mfma_f32_16x16x32_bf16(A1.s, B.s, c1, 0, 0, 0);
            union { short8 s; unsigned int u[4]; } a;
            a.u[0] = packbf2(fast_tanh(z0[0]), fast_tanh(z0[1]));
            a.u[1] = packbf2(fast_tanh(z0[2]), fast_tanh(z0[3]));
            a.u[2] = packbf2(fast_tanh(z1[0]), fast_tanh(z1[1]));
            a.u[3] = packbf2(fast_tanh(z1[2]), fast_tanh(z1[3]));
            acc[ti][0] = __builtin_amdgcn_mfma_f32_16x16x32_bf16(a.s, b0, acc[ti][0], 0, 0, 0);
            acc[ti][1] = __builtin_amdgcn_mfma_f32_16x16x32_bf16(a.s, b1, acc[ti][1], 0, 0, 0);
            acc[ti][2] = __builtin_amdgcn_mfma_f32_16x16x32_bf16(a.s, b2, acc[ti][2], 0, 0, 0);
        }
    }

    // epilogue: kmki/kevA[site][t][h]
    const float bo0 = b_kout[mi], bo1 = b_kout[16 + mi], bo2 = b_kout[32 + mi];
#pragma unroll
    for (int ti = 0; ti < 5; ++ti) {
        const int t = t0 + ti;
#pragma unroll
        for (int reg = 0; reg < 4; ++reg) {
            const int sl = quad * 4 + reg;
            float km = __expf(acc[ti][0][reg] + bo0);
            float ki = fmaxf(acc[ti][1][reg] + bo1, 0.f);
            float ke = __expf(acc[ti][2][reg] + bo2);
            float kev = ke * evS[wv][ti][sl] * geS[sl * 16 + mi];
            const int idx = ((s0 + sl) * 1000 + t) * 16 + mi;
            kmki[idx] = (unsigned int)f2bf(km) | ((unsigned int)f2bf(ki) << 16);
            kevA[idx] = f2bf(kev);
        }
    }
}

// ---------------- Kernel C v13: scan-only (conv/reduce split into kD) ----------------
// r6 post-mortem: lagged-conv bought only 9us; kC invariant ~220us across three
// structures. Separate the variables: kC keeps ONLY the t-serial scan (the
// irreducible recurrence) and writes q[site][t][h] f32 IN PLACE over kmki
// (region c of kmki is dead after SCANB(c) reads it from LDS; chunk c+1's DMA
// prefetch touches only region c+1 -- disjoint). ~40% of per-t instructions
// (conv 15 + dpp 4 + rotate 2 + y-store) leave kC; kD does them t-parallel.
// Decision rule: total ~430-465 => kC was issue-bound (keep shrinking it);
// total ~515-550 => stall mechanism unknown -> REP=2 counter diagnosis next.
#define KM_STRIDE 4160   // 4096 + 64 pad
#define KE_BASE   16640  // 4*4160
#define KE_STRIDE 2080   // 2048 + 32 pad
#define PS_BASE   24960  // 16640 + 4*2080
#define BUF_SZ    27008  // 24960 + 2048
__global__ __launch_bounds__(64, 1) void kC(
    const unsigned int* kmki,              // aliases qOut -- no restrict
    const ushort* __restrict__ kevA,
    const float2* __restrict__ pspl,
    const float* __restrict__ params, float* qOut)
{
    __shared__ char lds[2 * BUF_SZ];   // 54,016 B
    const int tid = threadIdx.x;
    const int sg = blockIdx.x;              // s_group (4 sites per wave)
    const int sl = tid >> 4;
    const int s = sg * 4 + sl;
    const int h = tid & 15;
    const int gid = s * 16 + h;

    const float kp  = params[0 * 32768 + gid];
    const float ks_ = params[1 * 32768 + gid];
    const float kd  = params[2 * 32768 + gid];
    const float gd  = params[3 * 32768 + gid];
    const float gl  = params[4 * 32768 + gid];
    const float qbv = params[5 * 32768 + gid];
    const float gi  = params[6 * 32768 + gid];
    const float gi1 = params[7 * 32768 + gid];
    const float kd1 = params[8 * 32768 + gid];
    const float gd1 = params[9 * 32768 + gid];

    float Sf = 0.f, Ss = 0.f, Sg = 0.f;
    float qcur[8];
#pragma unroll
    for (int i = 0; i < 8; ++i) qcur[i] = 0.f;

    const char* kmG = (const char*)kmki;   // [site][t][h] uint   -> 64 B/t/site
    const char* keG = (const char*)kevA;   // [site][t][h] ushort -> 32 B/t/site
    const char* psG = (const char*)pspl;   // [sg][t][sl] float2  -> 32 B/t

#define STAGE(c, TAIL) do {                                                     \
        char* L = lds + ((c) & 1) * BUF_SZ;                                     \
        _Pragma("unroll")                                                       \
        for (int q = 0; q < 4; ++q) {                                           \
            const char* gk = kmG + ((size_t)(sg * 4 + q) * 1000 + (c) * 64) * 64; \
            const char* ge = keG + ((size_t)(sg * 4 + q) * 1000 + (c) * 64) * 32; \
            char* lk = L + q * KM_STRIDE;                                       \
            char* le = L + KE_BASE + q * KE_STRIDE;                             \
            if (!(TAIL)) {                                                      \
                _Pragma("unroll")                                               \
                for (int k = 0; k < 4; ++k) gll16(gk + k * 1024 + tid * 16, lk + k * 1024); \
                _Pragma("unroll")                                               \
                for (int k = 0; k < 2; ++k) gll16(ge + k * 1024 + tid * 16, le + k * 1024); \
            } else {                                                            \
                _Pragma("unroll")                                               \
                for (int k = 0; k < 2; ++k) gll16(gk + k * 1024 + tid * 16, lk + k * 1024); \
                _Pragma("unroll")                                               \
                for (int k = 0; k < 2; ++k) gll4(gk + 2048 + k * 256 + tid * 4, lk + 2048 + k * 256); \
                gll16(ge + tid * 16, le);                                       \
                gll4(ge + 1024 + tid * 4, le + 1024);                           \
            }                                                                   \
        }                                                                       \
        const char* gp = psG + ((size_t)sg * 1000 + (c) * 64) * 32;             \
        char* lp = L + PS_BASE;                                                 \
        if (!(TAIL)) { gll16(gp + tid * 16, lp); gll16(gp + 1024 + tid * 16, lp + 1024); } \
        else         { gll16(gp + tid * 16, lp); gll4(gp + 1024 + tid * 4, lp + 1024); }   \
    } while (0)

    // scan batch (c, sb): fills qcur[0..7] from LDS buffer c&1
#define SCANB(c, sb) do {                                                       \
        const char* L = lds + ((c) & 1) * BUF_SZ;                               \
        const char* lk = L + sl * KM_STRIDE + h * 4 + (sb) * 512;               \
        const char* le = L + KE_BASE + sl * KE_STRIDE + h * 2 + (sb) * 256;     \
        const char* lp = L + PS_BASE + sl * 8 + (sb) * 256;                     \
        unsigned int a[8]; ushort e[8]; float2 p[8];                            \
        _Pragma("unroll")                                                       \
        for (int i = 0; i < 8; ++i) {                                           \
            a[i] = *(const unsigned int*)(lk + i * 64);                         \
            e[i] = *(const ushort*)(le + i * 32);                               \
            p[i] = *(const float2*)(lp + i * 32);                               \
        }                                                                       \
        _Pragma("unroll")                                                       \
        for (int i = 0; i < 8; ++i) {                                           \
            float km = __builtin_bit_cast(float, a[i] << 16);                   \
            float ki = __builtin_bit_cast(float, a[i] & 0xffff0000u);           \
            float kev = __builtin_bit_cast(float, ((unsigned int)e[i]) << 16);  \
            float ps = p[i].x, pl = p[i].y;                                     \
            Sf += ps;                                                           \
            float qf = fminf(Sf, km); Sf -= qf;                                 \
            float inflow = qf + pl;                                             \
            float qd = inflow * gi;                                             \
            Ss = fmaf(inflow, gi1, Ss);                                         \
            float E = fminf(Ss, kev); Ss -= E;                                  \
            float qi = fminf(ki, Ss); Ss -= qi;                                 \
            float qp = kp * fmaxf(Ss - gl, 0.f);                                \
            float qsa = ks_ * fminf(Ss, gl);                                    \
            Ss -= qp + qsa;                                                     \
            Sg = fmaf(qsa, gd, Sg);                                             \
            float qg = fmaf(kd, Sg, qbv);                                       \
            Sg *= kd1;                                                          \
            qcur[i] = fmaf(qsa, gd1, qp) + qg + qd + qi;                        \
        }                                                                       \
    } while (0)

    // store q batch to qOut[site][t][h] f32 (in-place over kmki region c)
#define STOREQ(c, sb) do {                                                      \
        const int tb = (c) * 64 + (sb) * 8;                                     \
        _Pragma("unroll")                                                       \
        for (int i = 0; i < 8; ++i)                                             \
            qOut[(size_t)s * 16000 + (size_t)(tb + i) * 16 + h] = qcur[i];      \
    } while (0)

    STAGE(0, false);
#pragma unroll 1
    for (int c = 0; c < 16; ++c) {
        if (c < 15) {
            if (c + 1 == 15) STAGE(15, true);
            else             STAGE(c + 1, false);
            asm volatile("s_waitcnt vmcnt(26)" ::: "memory");
        } else {
            asm volatile("s_waitcnt vmcnt(0)" ::: "memory");
        }
        const int NSB = (c == 15) ? 5 : 8;
#pragma unroll 1
        for (int sb = 0; sb < NSB; ++sb) {
            SCANB(c, sb);
            STOREQ(c, sb);
        }
        asm volatile("" ::: "memory");
    }
#undef STAGE
#undef SCANB
#undef STOREQ
}

// ---------------- Kernel D: conv + 16-lane reduce + store (fully t-parallel) ----------------
// grid = 512 sg x 8 t-chunks = 4096 waves (16 waves/CU). Reads q[site][t][h] f32
// (the kmki buffer, overwritten by kC), convolves over 8 t-taps, dpp-reduces the
// 16 heads, stores yOut. Halo batch handles cross-chunk taps; t<7 / t>=1000 guarded.
__global__ __launch_bounds__(64) void kD(
    const float* qOut,                     // aliases kmki -- no restrict
    const float* __restrict__ params, float* __restrict__ yOut)
{
    const int tid = threadIdx.x;
    const int sg = blockIdx.x >> 3;
    const int tc = blockIdx.x & 7;
    const int sl = tid >> 4, h = tid & 15;
    const int s = sg * 4 + sl;
    const int gid = s * 16 + h;
    float wrga[8];
#pragma unroll
    for (int i = 0; i < 8; ++i) wrga[i] = params[(11 + i) * 32768 + gid];
    const size_t sbase = (size_t)s * 16000;
    const int t0 = tc * 128;

    float qprev[8], qcur[8];
#pragma unroll
    for (int i = 0; i < 8; ++i) {
        int t = t0 - 8 + i; t = (t < 0) ? 0 : t;           // tc=0 garbage guarded by t>=7
        qprev[i] = qOut[sbase + (size_t)t * 16 + h];
    }
#pragma unroll 1
    for (int b = 0; b < 16; ++b) {
        const int tb = t0 + b * 8;
#pragma unroll
        for (int i = 0; i < 8; ++i) {
            int t = tb + i; t = (t > 999) ? 999 : t;       // tail garbage guarded by t<1000
            qcur[i] = qOut[sbase + (size_t)t * 16 + h];
        }
        float z[8];
#pragma unroll
        for (int i = 0; i < 8; ++i) {
            float za = wrga[6] * ((i >= 6) ? qcur[i - 6] : qprev[i + 2]);
            za = fmaf(wrga[4], (i >= 4) ? qcur[i - 4] : qprev[i + 4], za);
            za = fmaf(wrga[2], (i >= 2) ? qcur[i - 2] : qprev[i + 6], za);
            za = fmaf(wrga[0], qcur[i], za);
            float zb = wrga[7] * ((i >= 7) ? qcur[i - 7] : qprev[i + 1]);
            zb = fmaf(wrga[5], (i >= 5) ? qcur[i - 5] : qprev[i + 3], zb);
            zb = fmaf(wrga[3], (i >= 3) ? qcur[i - 3] : qprev[i + 5], zb);
            zb = fmaf(wrga[1], (i >= 1) ? qcur[i - 1] : qprev[i + 7], zb);
            z[i] = za + zb;
        }
#pragma unroll
        for (int i = 0; i < 8; ++i) z[i] = dpp_add<0xB1>(z[i]);
#pragma unroll
        for (int i = 0; i < 8; ++i) z[i] = dpp_add<0x4E>(z[i]);
#pragma unroll
        for (int i = 0; i < 8; ++i) z[i] = dpp_add<0x141>(z[i]);
#pragma unroll
        for (int i = 0; i < 8; ++i) z[i] = dpp_add<0x140>(z[i]);
        if (h == 0) {
#pragma unroll
            for (int i = 0; i < 8; ++i) {
                const int t = tb + i;
                if (t >= 7 && t < 1000) yOut[(t - 7) * 2048 + s] = z[i];
            }
        }
#pragma unroll
        for (int i = 0; i < 8; ++i) qprev[i] = qcur[i];
    }
}

// ---------------- launch ----------------
extern "C" void kernel_launch(void* const* d_in, const int* in_sizes, int n_in,
                              void* d_out, int out_size, void* d_ws, size_t ws_size,
                              hipStream_t stream) {
    const float* x      = (const float*)d_in[0];
    const float* xc     = (const float*)d_in[1];
    const float* W_fc   = (const float*)d_in[2];
    const float* b_fc   = (const float*)d_in[3];
    const float* W_r    = (const float*)d_in[4];
    const float* b_r    = (const float*)d_in[5];
    const float* W_g    = (const float*)d_in[6];
    const float* b_g    = (const float*)d_in[7];
    const float* W_kin  = (const float*)d_in[8];
    const float* b_kin  = (const float*)d_in[9];
    const float* W_kout = (const float*)d_in[10];
    const float* b_kout = (const float*)d_in[11];
    float* yOut = (float*)d_out;

    char* ws = (char*)d_ws;
    float*  stateK = (float*)(ws + 0);                        // 2 MB
    float*  params = (float*)(ws + (2 << 20));                // 19 planes (reserve 4 MB)
    ushort* Wt_g   = (ushort*)(ws + (6 << 20));               // 25,344 B
    ushort* whlo_g = (ushort*)(ws + (6 << 20) + (64 << 10));  // 4,096 B
    char*   p      = ws + (6 << 20) + (128 << 10);
    float2* pspl   = (float2*)p;                              // 16,384,000 B
    unsigned int* kmki = (unsigned int*)(p + 16384000);       // 131,072,000 B (reused as q f32 by kC/kD)
    ushort* kevA   = (ushort*)(p + 16384000 + 131072000);     //  65,536,000 B

    hipLaunchKernelGGL(kA, dim3(2048), dim3(256), 0, stream,
                       xc, W_fc, b_fc, W_r, b_r, W_g, b_g, W_kin, b_kin, W_kout,
                       stateK, params, Wt_g, whlo_g);
    hipLaunchKernelGGL(kB, dim3(128 * 50), dim3(256), 0, stream,
                       x, stateK, b_kout, Wt_g, whlo_g, params, kmki, kevA, pspl);
    hipLaunchKernelGGL(kC, dim3(512), dim3(64), 0, stream,
                       kmki, kevA, pspl, params, (float*)kmki);
    hipLaunchKernelGGL(kD, dim3(4096), dim3(64), 0, stream,
                       (const float*)kmki, params, yOut);
}